// Round 7
// baseline (148.592 us; speedup 1.0000x reference)
//
#include <hip/hip_runtime.h>

#define NTH 256

#define PHI1 0.29504296f    // e^{-1.220703125}
#define PHI2 0.0075683594f  // e^{-4.8828125}
#define GCUT 18.0f          // Gaussian support cutoff: e^-18 = 1.5e-8

// Bank swizzle — conflict-free for all in-place strides; swz(i+128)=swz(i)+128.
__device__ __forceinline__ int swz(int i) { return i ^ (((i >> 4) & 3) * 5); }

__device__ __forceinline__ float2 cmul(float2 a, float2 b) {
  return make_float2(a.x * b.x - a.y * b.y, a.x * b.y + a.y * b.x);
}

template <int W>
__device__ __forceinline__ float wsum(float v) {
#pragma unroll
  for (int off = 1; off < W; off <<= 1) v += __shfl_xor(v, off, 64);
  return v;
}

// P(idx): output frequency of storage slot idx after the radix-4 DIF sequence.
template <int M>
__device__ __forceinline__ int prevM(int i) {
  if (M == 128)
    return ((i >> 5) & 3) | (((i >> 3) & 3) << 2) | (((i >> 1) & 3) << 4) | ((i & 1) << 6);
  else if (M == 256)
    return ((i & 3) << 6) | (((i >> 2) & 3) << 4) | (((i >> 4) & 3) << 2) | ((i >> 6) & 3);
  else if (M == 512)
    return ((i >> 7) & 3) | (((i >> 5) & 3) << 2) | (((i >> 3) & 3) << 4) |
           (((i >> 1) & 3) << 6) | ((i & 1) << 8);
  else if (M == 1024)
    return ((i >> 8) & 3) | (((i >> 6) & 3) << 2) | (((i >> 4) & 3) << 4) |
           (((i >> 2) & 3) << 6) | ((i & 3) << 8);
  else
    return ((i >> 9) & 3) | (((i >> 7) & 3) << 2) | (((i >> 5) & 3) << 4) |
           (((i >> 3) & 3) << 6) | (((i >> 1) & 3) << 8) | ((i & 1) << 10);
}

// In-place radix-4 DIF stage; twiddles in registers.
template <bool INV>
__device__ __forceinline__ void dif4(float2* A, int j, int ls, float astep) {
  const int s = 1 << ls;
  const int e = j & (s - 1);
  const int base = ((j >> ls) << (ls + 2)) | e;
  float2 w1;
  __sincosf(astep * (float)e, &w1.y, &w1.x);
  if (INV) w1.y = -w1.y;
  const float2 w2 = cmul(w1, w1);
  const float2 w3 = cmul(w2, w1);
  const float2 a0 = A[swz(base)];
  const float2 a1 = A[swz(base + s)];
  const float2 a2 = A[swz(base + 2 * s)];
  const float2 a3 = A[swz(base + 3 * s)];
  const float t0x = a0.x + a2.x, t0y = a0.y + a2.y;
  const float t1x = a0.x - a2.x, t1y = a0.y - a2.y;
  const float t2x = a1.x + a3.x, t2y = a1.y + a3.y;
  const float bdx = a1.x - a3.x, bdy = a1.y - a3.y;
  const float sgn = INV ? -1.0f : 1.0f;
  const float t3x = sgn * bdy, t3y = -sgn * bdx;
  A[swz(base)]         = make_float2(t0x + t2x, t0y + t2y);
  A[swz(base + s)]     = cmul(make_float2(t1x + t3x, t1y + t3y), w1);
  A[swz(base + 2 * s)] = cmul(make_float2(t0x - t2x, t0y - t2y), w2);
  A[swz(base + 3 * s)] = cmul(make_float2(t1x - t3x, t1y - t3y), w3);
}

// In-place radix-4 DIT stage (transpose network; forward only).
__device__ __forceinline__ void dit4(float2* A, int j, int ls, float astep) {
  const int s = 1 << ls;
  const int e = j & (s - 1);
  const int base = ((j >> ls) << (ls + 2)) | e;
  float2 w1;
  __sincosf(astep * (float)e, &w1.y, &w1.x);
  const float2 w2 = cmul(w1, w1);
  const float2 w3 = cmul(w2, w1);
  const float2 c0 = A[swz(base)];
  const float2 c1 = cmul(A[swz(base + s)], w1);
  const float2 c2 = cmul(A[swz(base + 2 * s)], w2);
  const float2 c3 = cmul(A[swz(base + 3 * s)], w3);
  const float t0x = c0.x + c2.x, t0y = c0.y + c2.y;
  const float t1x = c0.x - c2.x, t1y = c0.y - c2.y;
  const float t2x = c1.x + c3.x, t2y = c1.y + c3.y;
  const float bdx = c1.x - c3.x, bdy = c1.y - c3.y;
  const float t3x = bdy, t3y = -bdx;
  A[swz(base)]         = make_float2(t0x + t2x, t0y + t2y);
  A[swz(base + s)]     = make_float2(t1x + t3x, t1y + t3y);
  A[swz(base + 2 * s)] = make_float2(t0x - t2x, t0y - t2y);
  A[swz(base + 3 * s)] = make_float2(t1x - t3x, t1y - t3y);
}

__device__ __forceinline__ void r2pair(float2* A, int g) {
  const float2 a = A[swz(2 * g)];
  const float2 b = A[swz(2 * g + 1)];
  A[swz(2 * g)]     = make_float2(a.x + b.x, a.y + b.y);
  A[swz(2 * g + 1)] = make_float2(a.x - b.x, a.y - b.y);
}

template <int M> struct LMof { static constexpr int v =
  (M == 2048) ? 11 : (M == 1024) ? 10 : (M == 512) ? 9 : (M == 256) ? 8 : 7; };

// Lane-group FFTs, barrier-free (group-private slice, in-order LDS pipe).
// Requires LANES <= M/4.
template <int M, bool INV, int LANES>
__device__ __forceinline__ void dif_w(float2* Aw, int l) {
  constexpr int LM = LMof<M>::v;
  constexpr int NB = M / 4;
#pragma unroll
  for (int ls = LM - 2; ls >= (LM & 1); ls -= 2) {
    const float astep = -1.5707963267948966f / (float)(1 << ls);
#pragma unroll
    for (int i = 0; i < NB / LANES; ++i) dif4<INV>(Aw, l + LANES * i, ls, astep);
  }
  if (LM & 1) {
#pragma unroll
    for (int i = 0; i < (M / 2) / LANES; ++i) r2pair(Aw, l + LANES * i);
  }
}

template <int M, int LANES>
__device__ __forceinline__ void dit_w(float2* Aw, int l) {
  constexpr int LM = LMof<M>::v;
  constexpr int NB = M / 4;
  if (LM & 1) {
#pragma unroll
    for (int i = 0; i < (M / 2) / LANES; ++i) r2pair(Aw, l + LANES * i);
  }
#pragma unroll
  for (int ls = (LM & 1); ls <= LM - 2; ls += 2) {
    const float astep = -1.5707963267948966f / (float)(1 << ls);
#pragma unroll
    for (int i = 0; i < NB / LANES; ++i) dit4(Aw, l + LANES * i, ls, astep);
  }
}

// ---------------- Stage A: 2048-pt block FFT per (b,c) signal --------------
__device__ __forceinline__ int prev2048(int i) {
  return ((i >> 9) & 3) | (((i >> 7) & 3) << 2) | (((i >> 5) & 3) << 4) |
         (((i >> 3) & 3) << 6) | (((i >> 1) & 3) << 8) | ((i & 1) << 10);
}

__global__ __launch_bounds__(NTH) void kA(const float* __restrict__ x,
                                          float2* __restrict__ xh) {
  __shared__ float2 A[2048];
  const int n = blockIdx.x, b = n / 6, c = n % 6;
  const float* xp = x + (size_t)b * (2048 * 6) + c;
#pragma unroll
  for (int i = 0; i < 8; ++i) {
    const int t = (int)threadIdx.x + NTH * i;
    A[swz(t)] = make_float2(xp[t * 6], 0.0f);
  }
  const int tid = (int)threadIdx.x;
#pragma unroll
  for (int ls = 9; ls >= 1; ls -= 2) {
    const float astep = -1.5707963267948966f / (float)(1 << ls);
    __syncthreads();
#pragma unroll
    for (int i = 0; i < 2; ++i) dif4<false>(A, tid + NTH * i, ls, astep);
  }
  __syncthreads();
#pragma unroll
  for (int i = 0; i < 4; ++i) r2pair(A, tid + NTH * i);
  __syncthreads();
#pragma unroll
  for (int i = 0; i < 8; ++i) {
    const int t = (int)threadIdx.x + NTH * i;
    xh[(size_t)n * 2048 + prev2048(t)] = A[swz(t)];
  }
}

// ---------------- output helpers ----------------
__device__ __forceinline__ float* o1p(float* out, int b, int c, int j1) {
  return out + ((size_t)b * 440 + j1) * 6 + c;
}
__device__ __forceinline__ float* o2p(float* out, int b, int c, int j1, int k) {
  return out + ((size_t)b * 440 + 80 + 4 * k * (k - 1) + j1) * 6 + c;
}
__device__ __forceinline__ float xi2f(int k) { return 0.4f * exp2f(-(float)k); }

// ---------------- parent: V into wave-local LDS slice; optional S1 --------
template <int M1, int LANES>
__device__ __forceinline__ void parent_w(float2* Vw, const float2* __restrict__ src,
                                         float* s1p, int j1, int l) {
  constexpr int NRW = M1 / LANES;
  constexpr int F = 2048 / M1;
  const float xi = 0.4f * exp2f(-0.125f * (float)j1);
  const float sig = 0.1f * xi;
  const float i2s = 1.0f / (2.0f * sig * sig);
#pragma unroll
  for (int i = 0; i < NRW; ++i) {
    const int m = l + LANES * i;
    float2 acc = make_float2(0.0f, 0.0f);
#pragma unroll
    for (int q = 0; q < F; ++q) {
      const int f = m + q * M1;
      const float fr = (float)(f < 1024 ? f : f - 2048) * (1.0f / 2048.0f);
      const float d = fr - xi;
      const float dd = d * d * i2s;
      if (dd < GCUT) {
        const float g = __expf(-dd);
        const float2 v = src[f];
        acc.x += v.x * g; acc.y += v.y * g;
      }
    }
    Vw[swz(m)] = acc;
  }
  dif_w<M1, true, LANES>(Vw, l);
#pragma unroll
  for (int i = 0; i < NRW; ++i) {
    const int m = l + LANES * i;
    const float2 zv = Vw[swz(m)];
    Vw[swz(m)] = make_float2(sqrtf(zv.x * zv.x + zv.y * zv.y) * (1.0f / 2048.0f), 0.0f);
  }
  dit_w<M1, LANES>(Vw, l);  // V natural (digit reversal cancels); stays in LDS.
  if (s1p) {
    const float invM = 1.0f / (float)M1;
    const float c0 = Vw[0].x * invM;  // swz identity for idx<16
    const float2 U1 = Vw[1], U2 = Vw[2];
    const float k1 = PHI1 * 2.0f * invM, k2 = PHI2 * 2.0f * invM;
    float part = 0.0f;
#pragma unroll
    for (int i = 0; i < NRW; ++i) {
      const int t = l + LANES * i;
      float sv, cv;
      __sincosf((6.283185307179586f / (float)M1) * (float)t, &sv, &cv);
      float acc = c0 + k1 * (U1.x * cv - U1.y * sv);
      const float c2 = cv * cv - sv * sv, s2 = 2.0f * sv * cv;
      acc += k2 * (U2.x * c2 - U2.y * s2);
      part += __logf(acc + 1e-6f);
    }
    part = wsum<LANES>(part);
    if (l == 0) *s1p = part * invM;
  }
}

// ---------------- descendant: fold V (in-place) + 3-bin DFT + log ----------
// In-place aliasing proof: read(r',q) = r'*LANES + l + q*M2; completed writes
// are r_w*LANES + l with r_w < r'; equality needs q*M2 = (r_w-r')*LANES < 0.
template <int M2, int LANES>
__device__ __forceinline__ void desc_ip(float2* Vw, float* __restrict__ outp,
                                        int M1, int F, float xi, int l) {
  constexpr int NR2 = M2 / LANES;
  const float sg = 0.8f * xi;
  const float i2s = 1.0f / (2.0f * sg * sg);
#pragma unroll
  for (int r = 0; r < NR2; ++r) {
    const int m = r * LANES + l;
    float2 acc = make_float2(0.0f, 0.0f);
    for (int q = 0; q < F; ++q) {
      const int f = m + q * M2;
      const float fr = (float)(f < (M1 >> 1) ? f : f - M1) * (1.0f / 2048.0f);
      const float d = fr - xi;
      const float dd = d * d * i2s;
      if (dd < GCUT) {
        const float g = __expf(-dd);
        const float2 vv = Vw[swz(f)];
        acc.x += vv.x * g; acc.y += vv.y * g;
      }
    }
    Vw[swz(m)] = acc;  // overwrites V[m]; safe per proof above
  }
  dif_w<M2, true, LANES>(Vw, l);  // z2 in P-order
  const float invM1f = 1.0f / (float)M1;
  float b0 = 0, b1r = 0, b1i = 0, b2r = 0, b2i = 0;
#pragma unroll
  for (int r = 0; r < NR2; ++r) {
    const int idx = r * LANES + l;
    const float2 zv = Vw[swz(idx)];
    const float u = sqrtf(zv.x * zv.x + zv.y * zv.y) * invM1f;
    const int t = prevM<M2>(idx);
    float sv, cv;
    __sincosf((6.283185307179586f / (float)M2) * (float)t, &sv, &cv);
    b0 += u;
    b1r += u * cv; b1i -= u * sv;
    const float c2 = cv * cv - sv * sv, s2 = 2.0f * sv * cv;
    b2r += u * c2; b2i -= u * s2;
  }
  b0 = wsum<LANES>(b0);
  b1r = wsum<LANES>(b1r); b1i = wsum<LANES>(b1i);
  b2r = wsum<LANES>(b2r); b2i = wsum<LANES>(b2i);
  const float k1 = 2.0f * PHI1, k2 = 2.0f * PHI2;
  const float invM2 = 1.0f / (float)M2;
  float part = 0.0f;
#pragma unroll
  for (int r = 0; r < NR2; ++r) {
    const int idx = r * LANES + l;
    const int t = prevM<M2>(idx);
    float sv, cv;
    __sincosf((6.283185307179586f / (float)M2) * (float)t, &sv, &cv);
    float acc = b0 + k1 * (b1r * cv - b1i * sv);
    const float c2 = cv * cv - sv * sv, s2 = 2.0f * sv * cv;
    acc += k2 * (b2r * c2 - b2i * s2);
    part += __logf(acc * invM2 + 1e-6f);
  }
  part = wsum<LANES>(part);
  if (l == 0) *outp = part * invM2;
}

// kU: unified B+C. One task per wave-unit; each task recomputes its parent V
// in its own LDS slice, then runs its descendant in place. No inter-block deps.
// Full-wave tasks ft in [0,192) (4/block, ci<48):
//   ft<72:   j1 = ft/9,        k = 1+ft%9,  M1=1024  (S1 when ft%9==0)
//   ft<136:  j1 = 8+(t>>3),    k = 2+(t&7), M1=512   (t = ft-72; S1 t&7==0)
//   else:    j1 = 16+t/7,      k = 3+t%7,   M1=256   (t = ft-136; S1 t%7==0)
// Half-wave tasks ht in [0,176) (8/block, ci>=48): octave o=3..9, M1=128;
//   pairs k=o+1..9 (S1 on first k); ht>=168: o=9 parent-only (no desc).
// LDS: 4 x 1024 float2 = 32 KB -> 5 blocks/CU; grid 3360 = 13.1 blocks/CU.
__global__ __launch_bounds__(NTH, 4) void kU(const float2* __restrict__ xh,
                                             float* __restrict__ out) {
  __shared__ float2 L[4096];  // 32 KB
  const int ci = (int)blockIdx.x / 48;
  const int n  = (int)blockIdx.x % 48;
  const int b = n / 6, c = n % 6;
  const float2* src = xh + (size_t)n * 2048;
  const int tid = (int)threadIdx.x;
  const int wid = tid >> 6, l = tid & 63;
  const int h = l >> 5, ll = l & 31;
  const int slot = 2 * wid + h;

  if (ci < 48) {  // ---- full-wave tasks ----
    const int ft = ci * 4 + wid;
    int j1, k, M1;
    bool s1;
    if (ft < 72) {
      j1 = ft / 9; k = 1 + ft % 9; M1 = 1024; s1 = (ft % 9 == 0);
    } else if (ft < 136) {
      const int t = ft - 72;
      j1 = 8 + (t >> 3); k = 2 + (t & 7); M1 = 512; s1 = ((t & 7) == 0);
    } else {
      const int t = ft - 136;
      j1 = 16 + t / 7; k = 3 + t % 7; M1 = 256; s1 = (t % 7 == 0);
    }
    float2* Vw = L + wid * 1024;
    float* s1ptr = s1 ? o1p(out, b, c, j1) : nullptr;
    if (M1 == 1024)      parent_w<1024, 64>(Vw, src, s1ptr, j1, l);
    else if (M1 == 512)  parent_w<512, 64>(Vw, src, s1ptr, j1, l);
    else                 parent_w<256, 64>(Vw, src, s1ptr, j1, l);
    const float xk = xi2f(k);
    float* op = o2p(out, b, c, j1, k);
    if (k == 1) {
      desc_ip<1024, 64>(Vw, op, 1024, 1, xk, l);
    } else if (k == 2) {
      desc_ip<512, 64>(Vw, op, M1, M1 >> 9, xk, l);
    } else if (k == 3) {
      if (M1 == 1024) desc_ip<512, 64>(Vw, op, 1024, 2, xk, l);
      else            desc_ip<256, 64>(Vw, op, M1, M1 >> 8, xk, l);
    } else if (k == 4 && M1 == 1024) {
      desc_ip<256, 64>(Vw, op, 1024, 4, xk, l);
    } else {
      if (h == 0) desc_ip<128, 32>(Vw, op, M1, M1 >> 7, xk, ll);
    }
  } else {  // ---- half-wave tasks, M1=128 ----
    const int ht = (ci - 48) * 8 + slot;
    int j1, k = 0;
    bool s1, havedesc = true;
    if (ht < 48)       { const int t = ht;       j1 = 24 + t / 6; k = 4 + t % 6; s1 = (t % 6 == 0); }
    else if (ht < 88)  { const int t = ht - 48;  j1 = 32 + t / 5; k = 5 + t % 5; s1 = (t % 5 == 0); }
    else if (ht < 120) { const int t = ht - 88;  j1 = 40 + (t >> 2); k = 6 + (t & 3); s1 = ((t & 3) == 0); }
    else if (ht < 144) { const int t = ht - 120; j1 = 48 + t / 3; k = 7 + t % 3; s1 = (t % 3 == 0); }
    else if (ht < 160) { const int t = ht - 144; j1 = 56 + (t >> 1); k = 8 + (t & 1); s1 = ((t & 1) == 0); }
    else if (ht < 168) { j1 = 64 + (ht - 160); k = 9; s1 = true; }
    else               { j1 = 72 + (ht - 168); s1 = true; havedesc = false; }
    float2* Vh = L + slot * 128;
    float* s1ptr = s1 ? o1p(out, b, c, j1) : nullptr;
    parent_w<128, 32>(Vh, src, s1ptr, j1, ll);
    if (havedesc)
      desc_ip<128, 32>(Vh, o2p(out, b, c, j1, k), 128, 1, xi2f(k), ll);
  }
}

extern "C" void kernel_launch(void* const* d_in, const int* in_sizes, int n_in,
                              void* d_out, int out_size, void* d_ws, size_t ws_size,
                              hipStream_t stream) {
  (void)in_sizes; (void)n_in; (void)out_size; (void)ws_size;
  const float* x = (const float*)d_in[0];  // [8, 2048, 6] fp32
  float* out = (float*)d_out;              // [8, 440, 6] fp32
  float2* xh = (float2*)d_ws;              // 48 * 2048 * 8 B = 786 KB
  kA<<<dim3(48), dim3(NTH), 0, stream>>>(x, xh);
  kU<<<dim3(70 * 48), dim3(NTH), 0, stream>>>(xh, out);
}

// Round 8
// 96.041 us; speedup vs baseline: 1.5472x; 1.5472x over previous
//
#include <hip/hip_runtime.h>

#define NTH 256
#define U1H_STRIDE 21504  // 8*1024 + 8*512 + 8*256 + 56*128

#define PHI1 0.29504296f    // e^{-1.220703125}
#define PHI2 0.0075683594f  // e^{-4.8828125}
#define GCUT 18.0f          // Gaussian support cutoff: e^-18 = 1.5e-8

// Bank swizzle — conflict-free for all in-place strides; swz(i+128)=swz(i)+128.
__device__ __forceinline__ int swz(int i) { return i ^ (((i >> 4) & 3) * 5); }

__device__ __forceinline__ float2 cmul(float2 a, float2 b) {
  return make_float2(a.x * b.x - a.y * b.y, a.x * b.y + a.y * b.x);
}

template <int W>
__device__ __forceinline__ float wsum(float v) {
#pragma unroll
  for (int off = 1; off < W; off <<= 1) v += __shfl_xor(v, off, 64);
  return v;
}

// P(idx): output frequency of storage slot idx after the DIF stage sequence.
template <int M>
__device__ __forceinline__ int prevM(int i) {
  if (M == 128)
    return ((i >> 5) & 3) | (((i >> 3) & 3) << 2) | (((i >> 1) & 3) << 4) | ((i & 1) << 6);
  else if (M == 256)
    return ((i & 3) << 6) | (((i >> 2) & 3) << 4) | (((i >> 4) & 3) << 2) | ((i >> 6) & 3);
  else if (M == 512)
    return ((i >> 7) & 3) | (((i >> 5) & 3) << 2) | (((i >> 3) & 3) << 4) |
           (((i >> 1) & 3) << 6) | ((i & 1) << 8);
  else if (M == 1024)
    return ((i >> 8) & 3) | (((i >> 6) & 3) << 2) | (((i >> 4) & 3) << 4) |
           (((i >> 2) & 3) << 6) | ((i & 3) << 8);
  else
    return ((i >> 9) & 3) | (((i >> 7) & 3) << 2) | (((i >> 5) & 3) << 4) |
           (((i >> 3) & 3) << 6) | (((i >> 1) & 3) << 8) | ((i & 1) << 10);
}

// In-place radix-4 DIF stage; twiddles in registers.
template <bool INV>
__device__ __forceinline__ void dif4(float2* A, int j, int ls, float astep) {
  const int s = 1 << ls;
  const int e = j & (s - 1);
  const int base = ((j >> ls) << (ls + 2)) | e;
  float2 w1;
  __sincosf(astep * (float)e, &w1.y, &w1.x);
  if (INV) w1.y = -w1.y;
  const float2 w2 = cmul(w1, w1);
  const float2 w3 = cmul(w2, w1);
  const float2 a0 = A[swz(base)];
  const float2 a1 = A[swz(base + s)];
  const float2 a2 = A[swz(base + 2 * s)];
  const float2 a3 = A[swz(base + 3 * s)];
  const float t0x = a0.x + a2.x, t0y = a0.y + a2.y;
  const float t1x = a0.x - a2.x, t1y = a0.y - a2.y;
  const float t2x = a1.x + a3.x, t2y = a1.y + a3.y;
  const float bdx = a1.x - a3.x, bdy = a1.y - a3.y;
  const float sgn = INV ? -1.0f : 1.0f;
  const float t3x = sgn * bdy, t3y = -sgn * bdx;
  A[swz(base)]         = make_float2(t0x + t2x, t0y + t2y);
  A[swz(base + s)]     = cmul(make_float2(t1x + t3x, t1y + t3y), w1);
  A[swz(base + 2 * s)] = cmul(make_float2(t0x - t2x, t0y - t2y), w2);
  A[swz(base + 3 * s)] = cmul(make_float2(t1x - t3x, t1y - t3y), w3);
}

// In-place radix-4 DIT stage (transpose network; forward only).
__device__ __forceinline__ void dit4(float2* A, int j, int ls, float astep) {
  const int s = 1 << ls;
  const int e = j & (s - 1);
  const int base = ((j >> ls) << (ls + 2)) | e;
  float2 w1;
  __sincosf(astep * (float)e, &w1.y, &w1.x);
  const float2 w2 = cmul(w1, w1);
  const float2 w3 = cmul(w2, w1);
  const float2 c0 = A[swz(base)];
  const float2 c1 = cmul(A[swz(base + s)], w1);
  const float2 c2 = cmul(A[swz(base + 2 * s)], w2);
  const float2 c3 = cmul(A[swz(base + 3 * s)], w3);
  const float t0x = c0.x + c2.x, t0y = c0.y + c2.y;
  const float t1x = c0.x - c2.x, t1y = c0.y - c2.y;
  const float t2x = c1.x + c3.x, t2y = c1.y + c3.y;
  const float bdx = c1.x - c3.x, bdy = c1.y - c3.y;
  const float t3x = bdy, t3y = -bdx;
  A[swz(base)]         = make_float2(t0x + t2x, t0y + t2y);
  A[swz(base + s)]     = make_float2(t1x + t3x, t1y + t3y);
  A[swz(base + 2 * s)] = make_float2(t0x - t2x, t0y - t2y);
  A[swz(base + 3 * s)] = make_float2(t1x - t3x, t1y - t3y);
}

__device__ __forceinline__ void r2pair(float2* A, int g) {
  const float2 a = A[swz(2 * g)];
  const float2 b = A[swz(2 * g + 1)];
  A[swz(2 * g)]     = make_float2(a.x + b.x, a.y + b.y);
  A[swz(2 * g + 1)] = make_float2(a.x - b.x, a.y - b.y);
}

template <int M> struct LMof { static constexpr int v =
  (M == 2048) ? 11 : (M == 1024) ? 10 : (M == 512) ? 9 : (M == 256) ? 8 : 7; };

// Block-wide in-place DIF: natural -> P-order.
template <int M, bool INV>
__device__ __forceinline__ void dif_blk(float2* A) {
  constexpr int LM = LMof<M>::v;
  constexpr int NB = M / 4;
  const int tid = (int)threadIdx.x;
#pragma unroll
  for (int ls = LM - 2; ls >= (LM & 1); ls -= 2) {
    const float astep = -1.5707963267948966f / (float)(1 << ls);
    __syncthreads();
#pragma unroll
    for (int i = 0; i < NB / NTH; ++i) dif4<INV>(A, tid + NTH * i, ls, astep);
  }
  if (LM & 1) {
    __syncthreads();
#pragma unroll
    for (int i = 0; i < (M / 2) / NTH; ++i) r2pair(A, tid + NTH * i);
  }
  __syncthreads();
}

// Block-wide in-place DIT (forward): P-order -> natural.
template <int M>
__device__ __forceinline__ void dit_blk(float2* A) {
  constexpr int LM = LMof<M>::v;
  constexpr int NB = M / 4;
  const int tid = (int)threadIdx.x;
  if (LM & 1) {
    __syncthreads();
#pragma unroll
    for (int i = 0; i < (M / 2) / NTH; ++i) r2pair(A, tid + NTH * i);
  }
#pragma unroll
  for (int ls = (LM & 1); ls <= LM - 2; ls += 2) {
    const float astep = -1.5707963267948966f / (float)(1 << ls);
    __syncthreads();
#pragma unroll
    for (int i = 0; i < NB / NTH; ++i) dit4(A, tid + NTH * i, ls, astep);
  }
  __syncthreads();
}

// Lane-group FFTs, barrier-free (group-private slice, in-order LDS pipe).
template <int M, bool INV, int LANES>
__device__ __forceinline__ void dif_w(float2* Aw, int l) {
  constexpr int LM = LMof<M>::v;
  constexpr int NB = M / 4;
#pragma unroll
  for (int ls = LM - 2; ls >= (LM & 1); ls -= 2) {
    const float astep = -1.5707963267948966f / (float)(1 << ls);
#pragma unroll
    for (int i = 0; i < NB / LANES; ++i) dif4<INV>(Aw, l + LANES * i, ls, astep);
  }
  if (LM & 1) {
#pragma unroll
    for (int i = 0; i < (M / 2) / LANES; ++i) r2pair(Aw, l + LANES * i);
  }
}

template <int M, int LANES>
__device__ __forceinline__ void dit_w(float2* Aw, int l) {
  constexpr int LM = LMof<M>::v;
  constexpr int NB = M / 4;
  if (LM & 1) {
#pragma unroll
    for (int i = 0; i < (M / 2) / LANES; ++i) r2pair(Aw, l + LANES * i);
  }
#pragma unroll
  for (int ls = (LM & 1); ls <= LM - 2; ls += 2) {
    const float astep = -1.5707963267948966f / (float)(1 << ls);
#pragma unroll
    for (int i = 0; i < NB / LANES; ++i) dit4(Aw, l + LANES * i, ls, astep);
  }
}

// U1h layout: o=0:1024/path; o=1:512; o=2:256; o>=3:128.
__device__ __forceinline__ int u1h_off(int j1) {
  const int o = j1 >> 3;
  if (o == 0) return j1 * 1024;
  if (o == 1) return 8192 + (j1 - 8) * 512;
  if (o == 2) return 12288 + (j1 - 16) * 256;
  return 14336 + (j1 - 24) * 128;
}

__device__ __forceinline__ float* o1p(float* out, int b, int c, int j1) {
  return out + ((size_t)b * 440 + j1) * 6 + c;
}
__device__ __forceinline__ float* o2p(float* out, int b, int c, int j1, int k) {
  return out + ((size_t)b * 440 + 80 + 4 * k * (k - 1) + j1) * 6 + c;
}
__device__ __forceinline__ float xi2f(int k) { return 0.4f * exp2f(-(float)k); }

// ---------------- Stage A: 2048-pt FFT per (b,c) signal ----------------
__global__ __launch_bounds__(NTH) void kA(const float* __restrict__ x,
                                          float2* __restrict__ xh) {
  __shared__ float2 A[2048];
  const int n = blockIdx.x, b = n / 6, c = n % 6;
  const float* xp = x + (size_t)b * (2048 * 6) + c;
#pragma unroll
  for (int i = 0; i < 8; ++i) {
    const int t = (int)threadIdx.x + NTH * i;
    A[swz(t)] = make_float2(xp[t * 6], 0.0f);
  }
  dif_blk<2048, false>(A);
#pragma unroll
  for (int i = 0; i < 8; ++i) {
    const int t = (int)threadIdx.x + NTH * i;
    xh[(size_t)n * 2048 + prevM<2048>(t)] = A[swz(t)];
  }
}

// ================= Stage B: parents; V=U1h -> global; S1 out ===============
// All bodies force-inlined, no cached sincos arrays (spill discipline, r2).

// Block-wide, M1=1024 (j1 0..7).
__device__ __forceinline__ void pblk1024(float2* A, float* scr,
                                         const float2* __restrict__ src,
                                         float2* __restrict__ Vg,
                                         float* __restrict__ outp, int j1) {
  constexpr int M1 = 1024;
  const int tid = (int)threadIdx.x;
  const float xi = 0.4f * exp2f(-0.125f * (float)j1);
  const float sig = 0.1f * xi;
  const float i2s = 1.0f / (2.0f * sig * sig);
#pragma unroll
  for (int i = 0; i < 4; ++i) {
    const int m = tid + NTH * i;
    float2 acc = make_float2(0.0f, 0.0f);
#pragma unroll
    for (int q = 0; q < 2; ++q) {
      const int f = m + q * M1;
      const float fr = (float)(f < 1024 ? f : f - 2048) * (1.0f / 2048.0f);
      const float d = fr - xi;
      const float dd = d * d * i2s;
      if (dd < GCUT) {
        const float g = __expf(-dd);
        const float2 v = src[f];
        acc.x += v.x * g; acc.y += v.y * g;
      }
    }
    A[swz(m)] = acc;
  }
  dif_blk<M1, true>(A);
#pragma unroll
  for (int i = 0; i < 4; ++i) {
    const int m = tid + NTH * i;
    const float2 zv = A[swz(m)];
    A[swz(m)] = make_float2(sqrtf(zv.x * zv.x + zv.y * zv.y) * (1.0f / 2048.0f), 0.0f);
  }
  dit_blk<M1>(A);  // V natural (digit reversal cancels).
#pragma unroll
  for (int i = 0; i < 4; ++i) {  // writeback V (coalesced, natural order)
    const int m = tid + NTH * i;
    Vg[m] = A[swz(m)];
  }
  const float invM = 1.0f / (float)M1;
  const float c0 = A[0].x * invM;  // swz identity for idx<16
  const float2 U1 = A[1], U2 = A[2];
  const float k1 = PHI1 * 2.0f * invM, k2 = PHI2 * 2.0f * invM;
  float part = 0.0f;
#pragma unroll
  for (int i = 0; i < 4; ++i) {
    const int t = tid + NTH * i;
    float sv, cv;
    __sincosf((6.283185307179586f / (float)M1) * (float)t, &sv, &cv);
    float acc = c0 + k1 * (U1.x * cv - U1.y * sv);
    const float c2 = cv * cv - sv * sv, s2 = 2.0f * sv * cv;
    acc += k2 * (U2.x * c2 - U2.y * s2);
    part += __logf(acc + 1e-6f);
  }
  part = wsum<64>(part);
  const int lane = tid & 63, wid = tid >> 6;
  if (lane == 0) scr[wid] = part;
  __syncthreads();
  if (tid == 0) *outp = (scr[0] + scr[1] + scr[2] + scr[3]) * invM;
}

// Per-wave (64 lanes), M1 in {512, 256}.
template <int M1>
__device__ __forceinline__ void pwav(float2* Aw, const float2* __restrict__ src,
                                     float2* __restrict__ Vg,
                                     float* __restrict__ outp, int j1, int l) {
  constexpr int NRW = M1 / 64;
  constexpr int F = 2048 / M1;
  const float xi = 0.4f * exp2f(-0.125f * (float)j1);
  const float sig = 0.1f * xi;
  const float i2s = 1.0f / (2.0f * sig * sig);
#pragma unroll
  for (int i = 0; i < NRW; ++i) {
    const int m = l + 64 * i;
    float2 acc = make_float2(0.0f, 0.0f);
#pragma unroll
    for (int q = 0; q < F; ++q) {
      const int f = m + q * M1;
      const float fr = (float)(f < 1024 ? f : f - 2048) * (1.0f / 2048.0f);
      const float d = fr - xi;
      const float dd = d * d * i2s;
      if (dd < GCUT) {
        const float g = __expf(-dd);
        const float2 v = src[f];
        acc.x += v.x * g; acc.y += v.y * g;
      }
    }
    Aw[swz(m)] = acc;
  }
  dif_w<M1, true, 64>(Aw, l);
#pragma unroll
  for (int i = 0; i < NRW; ++i) {
    const int m = l + 64 * i;
    const float2 zv = Aw[swz(m)];
    Aw[swz(m)] = make_float2(sqrtf(zv.x * zv.x + zv.y * zv.y) * (1.0f / 2048.0f), 0.0f);
  }
  dit_w<M1, 64>(Aw, l);  // V natural
#pragma unroll
  for (int i = 0; i < NRW; ++i) {
    const int m = l + 64 * i;
    Vg[m] = Aw[swz(m)];
  }
  const float invM = 1.0f / (float)M1;
  const float c0 = Aw[0].x * invM;
  const float2 U1 = Aw[1], U2 = Aw[2];
  const float k1 = PHI1 * 2.0f * invM, k2 = PHI2 * 2.0f * invM;
  float part = 0.0f;
#pragma unroll
  for (int i = 0; i < NRW; ++i) {
    const int t = l + 64 * i;
    float sv, cv;
    __sincosf((6.283185307179586f / (float)M1) * (float)t, &sv, &cv);
    float acc = c0 + k1 * (U1.x * cv - U1.y * sv);
    const float c2 = cv * cv - sv * sv, s2 = 2.0f * sv * cv;
    acc += k2 * (U2.x * c2 - U2.y * s2);
    part += __logf(acc + 1e-6f);
  }
  part = wsum<64>(part);
  if (l == 0) *outp = part * invM;
}

// Per-half-wave (32 lanes), M1=128.
__device__ __forceinline__ void pdual(float2* Ah, const float2* __restrict__ src,
                                      float2* __restrict__ Vg,
                                      float* __restrict__ outp, int j1, int ll) {
  const float xi = 0.4f * exp2f(-0.125f * (float)j1);
  const float sig = 0.1f * xi;
  const float i2s = 1.0f / (2.0f * sig * sig);
#pragma unroll
  for (int i = 0; i < 4; ++i) {
    const int m = ll + 32 * i;
    float2 acc = make_float2(0.0f, 0.0f);
#pragma unroll
    for (int q = 0; q < 16; ++q) {
      const int f = m + q * 128;
      const float fr = (float)(f < 1024 ? f : f - 2048) * (1.0f / 2048.0f);
      const float d = fr - xi;
      const float dd = d * d * i2s;
      if (dd < GCUT) {
        const float g = __expf(-dd);
        const float2 v = src[f];
        acc.x += v.x * g; acc.y += v.y * g;
      }
    }
    Ah[swz(m)] = acc;
  }
  dif_w<128, true, 32>(Ah, ll);
#pragma unroll
  for (int i = 0; i < 4; ++i) {
    const int m = ll + 32 * i;
    const float2 zv = Ah[swz(m)];
    Ah[swz(m)] = make_float2(sqrtf(zv.x * zv.x + zv.y * zv.y) * (1.0f / 2048.0f), 0.0f);
  }
  dit_w<128, 32>(Ah, ll);  // V natural
#pragma unroll
  for (int i = 0; i < 4; ++i) {
    const int m = ll + 32 * i;
    Vg[m] = Ah[swz(m)];
  }
  const float invM = 1.0f / 128.0f;
  const float c0 = Ah[0].x * invM;
  const float2 U1 = Ah[1], U2 = Ah[2];
  const float k1 = PHI1 * 2.0f * invM, k2 = PHI2 * 2.0f * invM;
  float part = 0.0f;
#pragma unroll
  for (int i = 0; i < 4; ++i) {
    const int t = ll + 32 * i;
    float sv, cv;
    __sincosf((6.283185307179586f / 128.0f) * (float)t, &sv, &cv);
    float acc = c0 + k1 * (U1.x * cv - U1.y * sv);
    const float c2 = cv * cv - sv * sv, s2 = 2.0f * sv * cv;
    acc += k2 * (U2.x * c2 - U2.y * s2);
    part += __logf(acc + 1e-6f);
  }
  part = wsum<32>(part);
  if (ll == 0) *outp = part * invM;
}

// kB: 19 classes/signal (912 blocks). LDS 2080 float2 = 16.6 KB.
// __launch_bounds__(NTH, 8): 8 waves/EU -> 8 blocks/CU (32 waves/CU, HW max);
// VGPR cap 64 = measured need of this code family (r4/r6/r7: 60-64, no arrays).
// [0,8) o=0 blk1024; [8,10) o=1 512wav x4; [10,12) o=2 256wav x4;
// [12,19) o>=3 128dual x8.
__global__ __launch_bounds__(NTH, 8) void kB(const float2* __restrict__ xh,
                                             float2* __restrict__ U1h,
                                             float* __restrict__ out) {
  __shared__ float2 A[2080];  // [2048,2080) = scratch floats
  const int ci = (int)blockIdx.x / 48;
  const int n  = (int)blockIdx.x % 48;
  const int b = n / 6, c = n % 6;
  const float2* src = xh + (size_t)n * 2048;
  float2* Vbase = U1h + (size_t)n * U1H_STRIDE;
  const int tid = (int)threadIdx.x;
  const int wid = tid >> 6, l = tid & 63;
  const int h = l >> 5, ll = l & 31;
  const int slot = 2 * wid + h;

  if (ci < 8) {
    const int j1 = ci;
    pblk1024(A, (float*)(A + 2048), src, Vbase + u1h_off(j1), o1p(out, b, c, j1), j1);
  } else if (ci < 10) {
    const int j1 = 8 + 4 * (ci - 8) + wid;
    pwav<512>(A + wid * 512, src, Vbase + u1h_off(j1), o1p(out, b, c, j1), j1, l);
  } else if (ci < 12) {
    const int j1 = 16 + 4 * (ci - 10) + wid;
    pwav<256>(A + wid * 256, src, Vbase + u1h_off(j1), o1p(out, b, c, j1), j1, l);
  } else {
    const int j1 = 24 + 8 * (ci - 12) + slot;
    pdual(A + slot * 128, src, Vbase + u1h_off(j1), o1p(out, b, c, j1), j1, ll);
  }
}

// ================= Stage C: descendants; V from global ====================

// Block-wide 3-bin DFT, M2=1024 (k=1 only; M1=1024, F=1).
__device__ __forceinline__ void dblk1024(float2* A, float* scr,
                                         const float2* __restrict__ Vg,
                                         float* __restrict__ outp, float xi) {
  constexpr int M2 = 1024;
  const int tid = (int)threadIdx.x;
  const float sg = 0.8f * xi;
  const float i2s = 1.0f / (2.0f * sg * sg);
#pragma unroll
  for (int ii = 0; ii < 4; ++ii) {
    const int m = tid + NTH * ii;
    float2 acc = make_float2(0.0f, 0.0f);
    const float fr = (float)(m < 512 ? m : m - 1024) * (1.0f / 2048.0f);
    const float d = fr - xi;
    const float dd = d * d * i2s;
    if (dd < GCUT) {
      const float g = __expf(-dd);
      const float2 vv = Vg[m];
      acc.x = vv.x * g; acc.y = vv.y * g;
    }
    A[swz(m)] = acc;
  }
  dif_blk<M2, true>(A);  // z2 in P-order
  const float invM1f = 1.0f / 1024.0f;
  float b0 = 0, b1r = 0, b1i = 0, b2r = 0, b2i = 0;
#pragma unroll
  for (int ii = 0; ii < 4; ++ii) {
    const int idx = tid + NTH * ii;
    const float2 zv = A[swz(idx)];
    const float u = sqrtf(zv.x * zv.x + zv.y * zv.y) * invM1f;
    const int t = prevM<M2>(idx);
    float sv, cv;
    __sincosf((6.283185307179586f / (float)M2) * (float)t, &sv, &cv);
    b0 += u;
    b1r += u * cv; b1i -= u * sv;
    const float c2 = cv * cv - sv * sv, s2 = 2.0f * sv * cv;
    b2r += u * c2; b2i -= u * s2;
  }
  b0 = wsum<64>(b0);
  b1r = wsum<64>(b1r); b1i = wsum<64>(b1i);
  b2r = wsum<64>(b2r); b2i = wsum<64>(b2i);
  const int lane = tid & 63, wid = tid >> 6;
  if (lane == 0) {
    scr[wid * 5 + 0] = b0;
    scr[wid * 5 + 1] = b1r; scr[wid * 5 + 2] = b1i;
    scr[wid * 5 + 3] = b2r; scr[wid * 5 + 4] = b2i;
  }
  __syncthreads();
  float Bv[5];
#pragma unroll
  for (int bi = 0; bi < 5; ++bi)
    Bv[bi] = scr[bi] + scr[5 + bi] + scr[10 + bi] + scr[15 + bi];
  const float k1 = 2.0f * PHI1, k2 = 2.0f * PHI2;
  const float invM2 = 1.0f / (float)M2;
  float part = 0.0f;
#pragma unroll
  for (int ii = 0; ii < 4; ++ii) {
    const int idx = tid + NTH * ii;
    const int t = prevM<M2>(idx);
    float sv, cv;
    __sincosf((6.283185307179586f / (float)M2) * (float)t, &sv, &cv);
    float acc = Bv[0] + k1 * (Bv[1] * cv - Bv[2] * sv);
    const float c2 = cv * cv - sv * sv, s2 = 2.0f * sv * cv;
    acc += k2 * (Bv[3] * c2 - Bv[4] * s2);
    part += __logf(acc * invM2 + 1e-6f);
  }
  part = wsum<64>(part);
  if (lane == 0) scr[20 + wid] = part;
  __syncthreads();
  if (tid == 0) *outp = (scr[20] + scr[21] + scr[22] + scr[23]) * invM2;
}

// Per-wave descendant, M2 in {512, 256}. No cached sincos arrays.
template <int M2>
__device__ __forceinline__ void dwav(float2* Aw, const float2* __restrict__ Vg,
                                     float* __restrict__ outp, int M1, int F,
                                     float xi, int l) {
  constexpr int NR2 = M2 / 64;
  const float sg = 0.8f * xi;
  const float i2s = 1.0f / (2.0f * sg * sg);
#pragma unroll
  for (int ii = 0; ii < NR2; ++ii) {
    const int m = l + 64 * ii;
    float2 acc = make_float2(0.0f, 0.0f);
    for (int q = 0; q < F; ++q) {
      const int f = m + q * M2;
      const float fr = (float)(f < (M1 >> 1) ? f : f - M1) * (1.0f / 2048.0f);
      const float d = fr - xi;
      const float dd = d * d * i2s;
      if (dd < GCUT) {
        const float g = __expf(-dd);
        const float2 vv = Vg[f];
        acc.x += vv.x * g; acc.y += vv.y * g;
      }
    }
    Aw[swz(m)] = acc;
  }
  dif_w<M2, true, 64>(Aw, l);
  const float invM1f = 1.0f / (float)M1;
  float b0 = 0, b1r = 0, b1i = 0, b2r = 0, b2i = 0;
#pragma unroll
  for (int ii = 0; ii < NR2; ++ii) {
    const int idx = l + 64 * ii;
    const float2 zv = Aw[swz(idx)];
    const float u = sqrtf(zv.x * zv.x + zv.y * zv.y) * invM1f;
    const int t = prevM<M2>(idx);
    float sv, cv;
    __sincosf((6.283185307179586f / (float)M2) * (float)t, &sv, &cv);
    b0 += u;
    b1r += u * cv; b1i -= u * sv;
    const float c2 = cv * cv - sv * sv, s2 = 2.0f * sv * cv;
    b2r += u * c2; b2i -= u * s2;
  }
  b0 = wsum<64>(b0);
  b1r = wsum<64>(b1r); b1i = wsum<64>(b1i);
  b2r = wsum<64>(b2r); b2i = wsum<64>(b2i);
  const float k1 = 2.0f * PHI1, k2 = 2.0f * PHI2;
  const float invM2 = 1.0f / (float)M2;
  float part = 0.0f;
#pragma unroll
  for (int ii = 0; ii < NR2; ++ii) {
    const int idx = l + 64 * ii;
    const int t = prevM<M2>(idx);
    float sv, cv;
    __sincosf((6.283185307179586f / (float)M2) * (float)t, &sv, &cv);
    float acc = b0 + k1 * (b1r * cv - b1i * sv);
    const float c2 = cv * cv - sv * sv, s2 = 2.0f * sv * cv;
    acc += k2 * (b2r * c2 - b2i * s2);
    part += __logf(acc * invM2 + 1e-6f);
  }
  part = wsum<64>(part);
  if (l == 0) *outp = part * invM2;
}

// Per-half-wave descendant, M2=128.
__device__ __forceinline__ void ddual(float2* Ah, const float2* __restrict__ Vg,
                                      float* __restrict__ outp, int M1, int F,
                                      float xi, int ll) {
  const float sg = 0.8f * xi;
  const float i2s = 1.0f / (2.0f * sg * sg);
#pragma unroll
  for (int ii = 0; ii < 4; ++ii) {
    const int m = ll + 32 * ii;
    float2 acc = make_float2(0.0f, 0.0f);
    for (int q = 0; q < F; ++q) {
      const int f = m + q * 128;
      const float fr = (float)(f < (M1 >> 1) ? f : f - M1) * (1.0f / 2048.0f);
      const float d = fr - xi;
      const float dd = d * d * i2s;
      if (dd < GCUT) {
        const float g = __expf(-dd);
        const float2 vv = Vg[f];
        acc.x += vv.x * g; acc.y += vv.y * g;
      }
    }
    Ah[swz(m)] = acc;
  }
  dif_w<128, true, 32>(Ah, ll);
  const float invM1f = 1.0f / (float)M1;
  float b0 = 0, b1r = 0, b1i = 0, b2r = 0, b2i = 0;
#pragma unroll
  for (int ii = 0; ii < 4; ++ii) {
    const int idx = ll + 32 * ii;
    const float2 zv = Ah[swz(idx)];
    const float u = sqrtf(zv.x * zv.x + zv.y * zv.y) * invM1f;
    const int t = prevM<128>(idx);
    float sv, cv;
    __sincosf((6.283185307179586f / 128.0f) * (float)t, &sv, &cv);
    b0 += u;
    b1r += u * cv; b1i -= u * sv;
    const float c2 = cv * cv - sv * sv, s2 = 2.0f * sv * cv;
    b2r += u * c2; b2i -= u * s2;
  }
  b0 = wsum<32>(b0);
  b1r = wsum<32>(b1r); b1i = wsum<32>(b1i);
  b2r = wsum<32>(b2r); b2i = wsum<32>(b2i);
  const float k1 = 2.0f * PHI1, k2 = 2.0f * PHI2;
  const float invM2 = 1.0f / 128.0f;
  float part = 0.0f;
#pragma unroll
  for (int ii = 0; ii < 4; ++ii) {
    const int idx = ll + 32 * ii;
    const int t = prevM<128>(idx);
    float sv, cv;
    __sincosf((6.283185307179586f / 128.0f) * (float)t, &sv, &cv);
    float acc = b0 + k1 * (b1r * cv - b1i * sv);
    const float c2 = cv * cv - sv * sv, s2 = 2.0f * sv * cv;
    acc += k2 * (b2r * c2 - b2i * s2);
    part += __logf(acc * invM2 + 1e-6f);
  }
  part = wsum<32>(part);
  if (ll == 0) *outp = part * invM2;
}

// kC: 58 classes/signal (2784 blocks), one descendant per slot, no chaining.
// __launch_bounds__(NTH, 8): 8 blocks/CU -> 2048 co-resident (was 1024).
// [0,8)   k=1: dblk1024, j1=ci.
// [8,12)  k=2: dwav<512> x4, j1=4(ci-8)+wid; M1 = j1<8?1024:512.
// [12,14) k=3 j1 0-7: dwav<512> x4, M1=1024 F=2.
// [14,18) k=3 j1 8-23: dwav<256> x4; M1 = j1<16?512:256.
// [18,20) k=4 j1 0-7: dwav<256> x4, M1=1024 F=4.
// [20,23) k=4 j1 8-31: ddual x8; M1 by octave.
// [23,58) k=5..9: ddual x8; k blocks per k.
__global__ __launch_bounds__(NTH, 8) void kC(const float2* __restrict__ U1h,
                                             float* __restrict__ out) {
  __shared__ float2 W[2048];
  __shared__ float scr[24];
  const int ci = (int)blockIdx.x / 48;
  const int n  = (int)blockIdx.x % 48;
  const int b = n / 6, c = n % 6;
  const float2* Vbase = U1h + (size_t)n * U1H_STRIDE;
  const int tid = (int)threadIdx.x;
  const int wid = tid >> 6, l = tid & 63;
  const int h = l >> 5, ll = l & 31;
  const int slot = 2 * wid + h;

  if (ci < 8) {
    const int j1 = ci;
    dblk1024(W, scr, Vbase + u1h_off(j1), o2p(out, b, c, j1, 1), xi2f(1));
  } else if (ci < 12) {
    const int j1 = 4 * (ci - 8) + wid;  // 0..15
    const int M1 = (j1 < 8) ? 1024 : 512;
    dwav<512>(W + wid * 512, Vbase + u1h_off(j1), o2p(out, b, c, j1, 2),
              M1, M1 / 512, xi2f(2), l);
  } else if (ci < 14) {
    const int j1 = 4 * (ci - 12) + wid;  // 0..7
    dwav<512>(W + wid * 512, Vbase + u1h_off(j1), o2p(out, b, c, j1, 3),
              1024, 2, xi2f(3), l);
  } else if (ci < 18) {
    const int j1 = 8 + 4 * (ci - 14) + wid;  // 8..23
    const int M1 = (j1 < 16) ? 512 : 256;
    dwav<256>(W + wid * 256, Vbase + u1h_off(j1), o2p(out, b, c, j1, 3),
              M1, M1 / 256, xi2f(3), l);
  } else if (ci < 20) {
    const int j1 = 4 * (ci - 18) + wid;  // 0..7
    dwav<256>(W + wid * 256, Vbase + u1h_off(j1), o2p(out, b, c, j1, 4),
              1024, 4, xi2f(4), l);
  } else if (ci < 23) {
    const int j1 = 8 + 8 * (ci - 20) + slot;  // 8..31
    const int o = j1 >> 3;                    // 1..3
    const int M1 = (o < 3) ? (1024 >> o) : 128;
    ddual(W + slot * 128, Vbase + u1h_off(j1), o2p(out, b, c, j1, 4),
          M1, M1 / 128, xi2f(4), ll);
  } else {
    int g = ci - 23;  // k blocks per k, k=5..9
    int k = 5;
    while (g >= k) { g -= k; ++k; }
    const int j1 = 8 * g + slot;  // octave o = g
    const int M1 = (g < 3) ? (1024 >> g) : 128;
    ddual(W + slot * 128, Vbase + u1h_off(j1), o2p(out, b, c, j1, k),
          M1, M1 / 128, xi2f(k), ll);
  }
}

extern "C" void kernel_launch(void* const* d_in, const int* in_sizes, int n_in,
                              void* d_out, int out_size, void* d_ws, size_t ws_size,
                              hipStream_t stream) {
  (void)in_sizes; (void)n_in; (void)out_size; (void)ws_size;
  const float* x = (const float*)d_in[0];  // [8, 2048, 6] fp32
  float* out = (float*)d_out;              // [8, 440, 6] fp32
  float2* U1h = (float2*)d_ws;                                       // 8.26 MB
  float2* xh = (float2*)((char*)d_ws + (size_t)48 * U1H_STRIDE * sizeof(float2));
  kA<<<dim3(48), dim3(NTH), 0, stream>>>(x, xh);
  kB<<<dim3(19 * 48), dim3(NTH), 0, stream>>>(xh, U1h, out);
  kC<<<dim3(58 * 48), dim3(NTH), 0, stream>>>(U1h, out);
}

// Round 9
// 84.801 us; speedup vs baseline: 1.7522x; 1.1325x over previous
//
#include <hip/hip_runtime.h>

#define NTH 256
#define U1H_STRIDE 21504  // 8*1024 + 8*512 + 8*256 + 56*128

#define PHI1 0.29504296f    // e^{-1.220703125}
#define PHI2 0.0075683594f  // e^{-4.8828125}
#define GCUT 18.0f          // Gaussian support cutoff: e^-18 = 1.5e-8

// Bank swizzle — conflict-free for all in-place strides; swz(i+128)=swz(i)+128.
__device__ __forceinline__ int swz(int i) { return i ^ (((i >> 4) & 3) * 5); }

__device__ __forceinline__ float2 cmul(float2 a, float2 b) {
  return make_float2(a.x * b.x - a.y * b.y, a.x * b.y + a.y * b.x);
}

template <int W>
__device__ __forceinline__ float wsum(float v) {
#pragma unroll
  for (int off = 1; off < W; off <<= 1) v += __shfl_xor(v, off, 64);
  return v;
}

// P(idx): output frequency of storage slot idx after the DIF stage sequence.
template <int M>
__device__ __forceinline__ int prevM(int i) {
  if (M == 128)
    return ((i >> 5) & 3) | (((i >> 3) & 3) << 2) | (((i >> 1) & 3) << 4) | ((i & 1) << 6);
  else if (M == 256)
    return ((i & 3) << 6) | (((i >> 2) & 3) << 4) | (((i >> 4) & 3) << 2) | ((i >> 6) & 3);
  else if (M == 512)
    return ((i >> 7) & 3) | (((i >> 5) & 3) << 2) | (((i >> 3) & 3) << 4) |
           (((i >> 1) & 3) << 6) | ((i & 1) << 8);
  else if (M == 1024)
    return ((i >> 8) & 3) | (((i >> 6) & 3) << 2) | (((i >> 4) & 3) << 4) |
           (((i >> 2) & 3) << 6) | ((i & 3) << 8);
  else
    return ((i >> 9) & 3) | (((i >> 7) & 3) << 2) | (((i >> 5) & 3) << 4) |
           (((i >> 3) & 3) << 6) | (((i >> 1) & 3) << 8) | ((i & 1) << 10);
}

// In-place radix-4 DIF stage; twiddles in registers.
template <bool INV>
__device__ __forceinline__ void dif4(float2* A, int j, int ls, float astep) {
  const int s = 1 << ls;
  const int e = j & (s - 1);
  const int base = ((j >> ls) << (ls + 2)) | e;
  float2 w1;
  __sincosf(astep * (float)e, &w1.y, &w1.x);
  if (INV) w1.y = -w1.y;
  const float2 w2 = cmul(w1, w1);
  const float2 w3 = cmul(w2, w1);
  const float2 a0 = A[swz(base)];
  const float2 a1 = A[swz(base + s)];
  const float2 a2 = A[swz(base + 2 * s)];
  const float2 a3 = A[swz(base + 3 * s)];
  const float t0x = a0.x + a2.x, t0y = a0.y + a2.y;
  const float t1x = a0.x - a2.x, t1y = a0.y - a2.y;
  const float t2x = a1.x + a3.x, t2y = a1.y + a3.y;
  const float bdx = a1.x - a3.x, bdy = a1.y - a3.y;
  const float sgn = INV ? -1.0f : 1.0f;
  const float t3x = sgn * bdy, t3y = -sgn * bdx;
  A[swz(base)]         = make_float2(t0x + t2x, t0y + t2y);
  A[swz(base + s)]     = cmul(make_float2(t1x + t3x, t1y + t3y), w1);
  A[swz(base + 2 * s)] = cmul(make_float2(t0x - t2x, t0y - t2y), w2);
  A[swz(base + 3 * s)] = cmul(make_float2(t1x - t3x, t1y - t3y), w3);
}

// In-place radix-4 DIT stage (transpose network; forward only).
__device__ __forceinline__ void dit4(float2* A, int j, int ls, float astep) {
  const int s = 1 << ls;
  const int e = j & (s - 1);
  const int base = ((j >> ls) << (ls + 2)) | e;
  float2 w1;
  __sincosf(astep * (float)e, &w1.y, &w1.x);
  const float2 w2 = cmul(w1, w1);
  const float2 w3 = cmul(w2, w1);
  const float2 c0 = A[swz(base)];
  const float2 c1 = cmul(A[swz(base + s)], w1);
  const float2 c2 = cmul(A[swz(base + 2 * s)], w2);
  const float2 c3 = cmul(A[swz(base + 3 * s)], w3);
  const float t0x = c0.x + c2.x, t0y = c0.y + c2.y;
  const float t1x = c0.x - c2.x, t1y = c0.y - c2.y;
  const float t2x = c1.x + c3.x, t2y = c1.y + c3.y;
  const float bdx = c1.x - c3.x, bdy = c1.y - c3.y;
  const float t3x = bdy, t3y = -bdx;
  A[swz(base)]         = make_float2(t0x + t2x, t0y + t2y);
  A[swz(base + s)]     = make_float2(t1x + t3x, t1y + t3y);
  A[swz(base + 2 * s)] = make_float2(t0x - t2x, t0y - t2y);
  A[swz(base + 3 * s)] = make_float2(t1x - t3x, t1y - t3y);
}

__device__ __forceinline__ void r2pair(float2* A, int g) {
  const float2 a = A[swz(2 * g)];
  const float2 b = A[swz(2 * g + 1)];
  A[swz(2 * g)]     = make_float2(a.x + b.x, a.y + b.y);
  A[swz(2 * g + 1)] = make_float2(a.x - b.x, a.y - b.y);
}

template <int M> struct LMof { static constexpr int v =
  (M == 2048) ? 11 : (M == 1024) ? 10 : (M == 512) ? 9 : (M == 256) ? 8 : 7; };

// Block-wide in-place DIF: natural -> P-order.
template <int M, bool INV>
__device__ __forceinline__ void dif_blk(float2* A) {
  constexpr int LM = LMof<M>::v;
  constexpr int NB = M / 4;
  const int tid = (int)threadIdx.x;
#pragma unroll
  for (int ls = LM - 2; ls >= (LM & 1); ls -= 2) {
    const float astep = -1.5707963267948966f / (float)(1 << ls);
    __syncthreads();
#pragma unroll
    for (int i = 0; i < NB / NTH; ++i) dif4<INV>(A, tid + NTH * i, ls, astep);
  }
  if (LM & 1) {
    __syncthreads();
#pragma unroll
    for (int i = 0; i < (M / 2) / NTH; ++i) r2pair(A, tid + NTH * i);
  }
  __syncthreads();
}

// Block-wide in-place DIT (forward): P-order -> natural.
template <int M>
__device__ __forceinline__ void dit_blk(float2* A) {
  constexpr int LM = LMof<M>::v;
  constexpr int NB = M / 4;
  const int tid = (int)threadIdx.x;
  if (LM & 1) {
    __syncthreads();
#pragma unroll
    for (int i = 0; i < (M / 2) / NTH; ++i) r2pair(A, tid + NTH * i);
  }
#pragma unroll
  for (int ls = (LM & 1); ls <= LM - 2; ls += 2) {
    const float astep = -1.5707963267948966f / (float)(1 << ls);
    __syncthreads();
#pragma unroll
    for (int i = 0; i < NB / NTH; ++i) dit4(A, tid + NTH * i, ls, astep);
  }
  __syncthreads();
}

// Lane-group FFTs, barrier-free (group-private slice, in-order LDS pipe).
template <int M, bool INV, int LANES>
__device__ __forceinline__ void dif_w(float2* Aw, int l) {
  constexpr int LM = LMof<M>::v;
  constexpr int NB = M / 4;
#pragma unroll
  for (int ls = LM - 2; ls >= (LM & 1); ls -= 2) {
    const float astep = -1.5707963267948966f / (float)(1 << ls);
#pragma unroll
    for (int i = 0; i < NB / LANES; ++i) dif4<INV>(Aw, l + LANES * i, ls, astep);
  }
  if (LM & 1) {
#pragma unroll
    for (int i = 0; i < (M / 2) / LANES; ++i) r2pair(Aw, l + LANES * i);
  }
}

template <int M, int LANES>
__device__ __forceinline__ void dit_w(float2* Aw, int l) {
  constexpr int LM = LMof<M>::v;
  constexpr int NB = M / 4;
  if (LM & 1) {
#pragma unroll
    for (int i = 0; i < (M / 2) / LANES; ++i) r2pair(Aw, l + LANES * i);
  }
#pragma unroll
  for (int ls = (LM & 1); ls <= LM - 2; ls += 2) {
    const float astep = -1.5707963267948966f / (float)(1 << ls);
#pragma unroll
    for (int i = 0; i < NB / LANES; ++i) dit4(Aw, l + LANES * i, ls, astep);
  }
}

// U1h layout: o=0:1024/path; o=1:512; o=2:256; o>=3:128.
__device__ __forceinline__ int u1h_off(int j1) {
  const int o = j1 >> 3;
  if (o == 0) return j1 * 1024;
  if (o == 1) return 8192 + (j1 - 8) * 512;
  if (o == 2) return 12288 + (j1 - 16) * 256;
  return 14336 + (j1 - 24) * 128;
}

__device__ __forceinline__ float* o1p(float* out, int b, int c, int j1) {
  return out + ((size_t)b * 440 + j1) * 6 + c;
}
__device__ __forceinline__ float* o2p(float* out, int b, int c, int j1, int k) {
  return out + ((size_t)b * 440 + 80 + 4 * k * (k - 1) + j1) * 6 + c;
}
__device__ __forceinline__ float xi2f(int k) { return 0.4f * exp2f(-(float)k); }

// ---------------- Stage A: 2048-pt FFT per (b,c) signal ----------------
__global__ __launch_bounds__(NTH) void kA(const float* __restrict__ x,
                                          float2* __restrict__ xh) {
  __shared__ float2 A[2048];
  const int n = blockIdx.x, b = n / 6, c = n % 6;
  const float* xp = x + (size_t)b * (2048 * 6) + c;
#pragma unroll
  for (int i = 0; i < 8; ++i) {
    const int t = (int)threadIdx.x + NTH * i;
    A[swz(t)] = make_float2(xp[t * 6], 0.0f);
  }
  dif_blk<2048, false>(A);
#pragma unroll
  for (int i = 0; i < 8; ++i) {
    const int t = (int)threadIdx.x + NTH * i;
    xh[(size_t)n * 2048 + prevM<2048>(t)] = A[swz(t)];
  }
}

// ================= Stage B: parents; V=U1h -> global; S1 out ===============
// All bodies force-inlined, no cached sincos arrays (spill discipline, r2).

// Block-wide, M1=1024 (j1 0..7).
__device__ __forceinline__ void pblk1024(float2* A, float* scr,
                                         const float2* __restrict__ src,
                                         float2* __restrict__ Vg,
                                         float* __restrict__ outp, int j1) {
  constexpr int M1 = 1024;
  const int tid = (int)threadIdx.x;
  const float xi = 0.4f * exp2f(-0.125f * (float)j1);
  const float sig = 0.1f * xi;
  const float i2s = 1.0f / (2.0f * sig * sig);
#pragma unroll
  for (int i = 0; i < 4; ++i) {
    const int m = tid + NTH * i;
    float2 acc = make_float2(0.0f, 0.0f);
#pragma unroll
    for (int q = 0; q < 2; ++q) {
      const int f = m + q * M1;
      const float fr = (float)(f < 1024 ? f : f - 2048) * (1.0f / 2048.0f);
      const float d = fr - xi;
      const float dd = d * d * i2s;
      if (dd < GCUT) {
        const float g = __expf(-dd);
        const float2 v = src[f];
        acc.x += v.x * g; acc.y += v.y * g;
      }
    }
    A[swz(m)] = acc;
  }
  dif_blk<M1, true>(A);
#pragma unroll
  for (int i = 0; i < 4; ++i) {
    const int m = tid + NTH * i;
    const float2 zv = A[swz(m)];
    A[swz(m)] = make_float2(sqrtf(zv.x * zv.x + zv.y * zv.y) * (1.0f / 2048.0f), 0.0f);
  }
  dit_blk<M1>(A);  // V natural (digit reversal cancels).
#pragma unroll
  for (int i = 0; i < 4; ++i) {  // writeback V (coalesced, natural order)
    const int m = tid + NTH * i;
    Vg[m] = A[swz(m)];
  }
  const float invM = 1.0f / (float)M1;
  const float c0 = A[0].x * invM;  // swz identity for idx<16
  const float2 U1 = A[1], U2 = A[2];
  const float k1 = PHI1 * 2.0f * invM, k2 = PHI2 * 2.0f * invM;
  float part = 0.0f;
#pragma unroll
  for (int i = 0; i < 4; ++i) {
    const int t = tid + NTH * i;
    float sv, cv;
    __sincosf((6.283185307179586f / (float)M1) * (float)t, &sv, &cv);
    float acc = c0 + k1 * (U1.x * cv - U1.y * sv);
    const float c2 = cv * cv - sv * sv, s2 = 2.0f * sv * cv;
    acc += k2 * (U2.x * c2 - U2.y * s2);
    part += __logf(acc + 1e-6f);
  }
  part = wsum<64>(part);
  const int lane = tid & 63, wid = tid >> 6;
  if (lane == 0) scr[wid] = part;
  __syncthreads();
  if (tid == 0) *outp = (scr[0] + scr[1] + scr[2] + scr[3]) * invM;
}

// Per-wave (64 lanes), M1 in {512, 256}.
template <int M1>
__device__ __forceinline__ void pwav(float2* Aw, const float2* __restrict__ src,
                                     float2* __restrict__ Vg,
                                     float* __restrict__ outp, int j1, int l) {
  constexpr int NRW = M1 / 64;
  constexpr int F = 2048 / M1;
  const float xi = 0.4f * exp2f(-0.125f * (float)j1);
  const float sig = 0.1f * xi;
  const float i2s = 1.0f / (2.0f * sig * sig);
#pragma unroll
  for (int i = 0; i < NRW; ++i) {
    const int m = l + 64 * i;
    float2 acc = make_float2(0.0f, 0.0f);
#pragma unroll
    for (int q = 0; q < F; ++q) {
      const int f = m + q * M1;
      const float fr = (float)(f < 1024 ? f : f - 2048) * (1.0f / 2048.0f);
      const float d = fr - xi;
      const float dd = d * d * i2s;
      if (dd < GCUT) {
        const float g = __expf(-dd);
        const float2 v = src[f];
        acc.x += v.x * g; acc.y += v.y * g;
      }
    }
    Aw[swz(m)] = acc;
  }
  dif_w<M1, true, 64>(Aw, l);
#pragma unroll
  for (int i = 0; i < NRW; ++i) {
    const int m = l + 64 * i;
    const float2 zv = Aw[swz(m)];
    Aw[swz(m)] = make_float2(sqrtf(zv.x * zv.x + zv.y * zv.y) * (1.0f / 2048.0f), 0.0f);
  }
  dit_w<M1, 64>(Aw, l);  // V natural
#pragma unroll
  for (int i = 0; i < NRW; ++i) {
    const int m = l + 64 * i;
    Vg[m] = Aw[swz(m)];
  }
  const float invM = 1.0f / (float)M1;
  const float c0 = Aw[0].x * invM;
  const float2 U1 = Aw[1], U2 = Aw[2];
  const float k1 = PHI1 * 2.0f * invM, k2 = PHI2 * 2.0f * invM;
  float part = 0.0f;
#pragma unroll
  for (int i = 0; i < NRW; ++i) {
    const int t = l + 64 * i;
    float sv, cv;
    __sincosf((6.283185307179586f / (float)M1) * (float)t, &sv, &cv);
    float acc = c0 + k1 * (U1.x * cv - U1.y * sv);
    const float c2 = cv * cv - sv * sv, s2 = 2.0f * sv * cv;
    acc += k2 * (U2.x * c2 - U2.y * s2);
    part += __logf(acc + 1e-6f);
  }
  part = wsum<64>(part);
  if (l == 0) *outp = part * invM;
}

// Per-half-wave (32 lanes), M1=128.
__device__ __forceinline__ void pdual(float2* Ah, const float2* __restrict__ src,
                                      float2* __restrict__ Vg,
                                      float* __restrict__ outp, int j1, int ll) {
  const float xi = 0.4f * exp2f(-0.125f * (float)j1);
  const float sig = 0.1f * xi;
  const float i2s = 1.0f / (2.0f * sig * sig);
#pragma unroll
  for (int i = 0; i < 4; ++i) {
    const int m = ll + 32 * i;
    float2 acc = make_float2(0.0f, 0.0f);
#pragma unroll
    for (int q = 0; q < 16; ++q) {
      const int f = m + q * 128;
      const float fr = (float)(f < 1024 ? f : f - 2048) * (1.0f / 2048.0f);
      const float d = fr - xi;
      const float dd = d * d * i2s;
      if (dd < GCUT) {
        const float g = __expf(-dd);
        const float2 v = src[f];
        acc.x += v.x * g; acc.y += v.y * g;
      }
    }
    Ah[swz(m)] = acc;
  }
  dif_w<128, true, 32>(Ah, ll);
#pragma unroll
  for (int i = 0; i < 4; ++i) {
    const int m = ll + 32 * i;
    const float2 zv = Ah[swz(m)];
    Ah[swz(m)] = make_float2(sqrtf(zv.x * zv.x + zv.y * zv.y) * (1.0f / 2048.0f), 0.0f);
  }
  dit_w<128, 32>(Ah, ll);  // V natural
#pragma unroll
  for (int i = 0; i < 4; ++i) {
    const int m = ll + 32 * i;
    Vg[m] = Ah[swz(m)];
  }
  const float invM = 1.0f / 128.0f;
  const float c0 = Ah[0].x * invM;
  const float2 U1 = Ah[1], U2 = Ah[2];
  const float k1 = PHI1 * 2.0f * invM, k2 = PHI2 * 2.0f * invM;
  float part = 0.0f;
#pragma unroll
  for (int i = 0; i < 4; ++i) {
    const int t = ll + 32 * i;
    float sv, cv;
    __sincosf((6.283185307179586f / 128.0f) * (float)t, &sv, &cv);
    float acc = c0 + k1 * (U1.x * cv - U1.y * sv);
    const float c2 = cv * cv - sv * sv, s2 = 2.0f * sv * cv;
    acc += k2 * (U2.x * c2 - U2.y * s2);
    part += __logf(acc + 1e-6f);
  }
  part = wsum<32>(part);
  if (ll == 0) *outp = part * invM;
}

// kB: 19 classes/signal (912 blocks). LDS 2080 float2 = 16.6 KB.
// __launch_bounds__(NTH, 4): verified optimum (r5 = 83.9 µs); bound 8 regressed
// (r8: VGPR cap 64 < need -> spill/sched loss, +12 µs).
// [0,8) o=0 blk1024; [8,10) o=1 512wav x4; [10,12) o=2 256wav x4;
// [12,19) o>=3 128dual x8.
__global__ __launch_bounds__(NTH, 4) void kB(const float2* __restrict__ xh,
                                             float2* __restrict__ U1h,
                                             float* __restrict__ out) {
  __shared__ float2 A[2080];  // [2048,2080) = scratch floats
  const int ci = (int)blockIdx.x / 48;
  const int n  = (int)blockIdx.x % 48;
  const int b = n / 6, c = n % 6;
  const float2* src = xh + (size_t)n * 2048;
  float2* Vbase = U1h + (size_t)n * U1H_STRIDE;
  const int tid = (int)threadIdx.x;
  const int wid = tid >> 6, l = tid & 63;
  const int h = l >> 5, ll = l & 31;
  const int slot = 2 * wid + h;

  if (ci < 8) {
    const int j1 = ci;
    pblk1024(A, (float*)(A + 2048), src, Vbase + u1h_off(j1), o1p(out, b, c, j1), j1);
  } else if (ci < 10) {
    const int j1 = 8 + 4 * (ci - 8) + wid;
    pwav<512>(A + wid * 512, src, Vbase + u1h_off(j1), o1p(out, b, c, j1), j1, l);
  } else if (ci < 12) {
    const int j1 = 16 + 4 * (ci - 10) + wid;
    pwav<256>(A + wid * 256, src, Vbase + u1h_off(j1), o1p(out, b, c, j1), j1, l);
  } else {
    const int j1 = 24 + 8 * (ci - 12) + slot;
    pdual(A + slot * 128, src, Vbase + u1h_off(j1), o1p(out, b, c, j1), j1, ll);
  }
}

// ================= Stage C: descendants; V from global ====================

// Block-wide 3-bin DFT, M2=1024 (k=1 only; M1=1024, F=1).
__device__ __forceinline__ void dblk1024(float2* A, float* scr,
                                         const float2* __restrict__ Vg,
                                         float* __restrict__ outp, float xi) {
  constexpr int M2 = 1024;
  const int tid = (int)threadIdx.x;
  const float sg = 0.8f * xi;
  const float i2s = 1.0f / (2.0f * sg * sg);
#pragma unroll
  for (int ii = 0; ii < 4; ++ii) {
    const int m = tid + NTH * ii;
    float2 acc = make_float2(0.0f, 0.0f);
    const float fr = (float)(m < 512 ? m : m - 1024) * (1.0f / 2048.0f);
    const float d = fr - xi;
    const float dd = d * d * i2s;
    if (dd < GCUT) {
      const float g = __expf(-dd);
      const float2 vv = Vg[m];
      acc.x = vv.x * g; acc.y = vv.y * g;
    }
    A[swz(m)] = acc;
  }
  dif_blk<M2, true>(A);  // z2 in P-order
  const float invM1f = 1.0f / 1024.0f;
  float b0 = 0, b1r = 0, b1i = 0, b2r = 0, b2i = 0;
#pragma unroll
  for (int ii = 0; ii < 4; ++ii) {
    const int idx = tid + NTH * ii;
    const float2 zv = A[swz(idx)];
    const float u = sqrtf(zv.x * zv.x + zv.y * zv.y) * invM1f;
    const int t = prevM<M2>(idx);
    float sv, cv;
    __sincosf((6.283185307179586f / (float)M2) * (float)t, &sv, &cv);
    b0 += u;
    b1r += u * cv; b1i -= u * sv;
    const float c2 = cv * cv - sv * sv, s2 = 2.0f * sv * cv;
    b2r += u * c2; b2i -= u * s2;
  }
  b0 = wsum<64>(b0);
  b1r = wsum<64>(b1r); b1i = wsum<64>(b1i);
  b2r = wsum<64>(b2r); b2i = wsum<64>(b2i);
  const int lane = tid & 63, wid = tid >> 6;
  if (lane == 0) {
    scr[wid * 5 + 0] = b0;
    scr[wid * 5 + 1] = b1r; scr[wid * 5 + 2] = b1i;
    scr[wid * 5 + 3] = b2r; scr[wid * 5 + 4] = b2i;
  }
  __syncthreads();
  float Bv[5];
#pragma unroll
  for (int bi = 0; bi < 5; ++bi)
    Bv[bi] = scr[bi] + scr[5 + bi] + scr[10 + bi] + scr[15 + bi];
  const float k1 = 2.0f * PHI1, k2 = 2.0f * PHI2;
  const float invM2 = 1.0f / (float)M2;
  float part = 0.0f;
#pragma unroll
  for (int ii = 0; ii < 4; ++ii) {
    const int idx = tid + NTH * ii;
    const int t = prevM<M2>(idx);
    float sv, cv;
    __sincosf((6.283185307179586f / (float)M2) * (float)t, &sv, &cv);
    float acc = Bv[0] + k1 * (Bv[1] * cv - Bv[2] * sv);
    const float c2 = cv * cv - sv * sv, s2 = 2.0f * sv * cv;
    acc += k2 * (Bv[3] * c2 - Bv[4] * s2);
    part += __logf(acc * invM2 + 1e-6f);
  }
  part = wsum<64>(part);
  if (lane == 0) scr[20 + wid] = part;
  __syncthreads();
  if (tid == 0) *outp = (scr[20] + scr[21] + scr[22] + scr[23]) * invM2;
}

// Per-wave descendant, M2 in {512, 256}. No cached sincos arrays.
template <int M2>
__device__ __forceinline__ void dwav(float2* Aw, const float2* __restrict__ Vg,
                                     float* __restrict__ outp, int M1, int F,
                                     float xi, int l) {
  constexpr int NR2 = M2 / 64;
  const float sg = 0.8f * xi;
  const float i2s = 1.0f / (2.0f * sg * sg);
#pragma unroll
  for (int ii = 0; ii < NR2; ++ii) {
    const int m = l + 64 * ii;
    float2 acc = make_float2(0.0f, 0.0f);
    for (int q = 0; q < F; ++q) {
      const int f = m + q * M2;
      const float fr = (float)(f < (M1 >> 1) ? f : f - M1) * (1.0f / 2048.0f);
      const float d = fr - xi;
      const float dd = d * d * i2s;
      if (dd < GCUT) {
        const float g = __expf(-dd);
        const float2 vv = Vg[f];
        acc.x += vv.x * g; acc.y += vv.y * g;
      }
    }
    Aw[swz(m)] = acc;
  }
  dif_w<M2, true, 64>(Aw, l);
  const float invM1f = 1.0f / (float)M1;
  float b0 = 0, b1r = 0, b1i = 0, b2r = 0, b2i = 0;
#pragma unroll
  for (int ii = 0; ii < NR2; ++ii) {
    const int idx = l + 64 * ii;
    const float2 zv = Aw[swz(idx)];
    const float u = sqrtf(zv.x * zv.x + zv.y * zv.y) * invM1f;
    const int t = prevM<M2>(idx);
    float sv, cv;
    __sincosf((6.283185307179586f / (float)M2) * (float)t, &sv, &cv);
    b0 += u;
    b1r += u * cv; b1i -= u * sv;
    const float c2 = cv * cv - sv * sv, s2 = 2.0f * sv * cv;
    b2r += u * c2; b2i -= u * s2;
  }
  b0 = wsum<64>(b0);
  b1r = wsum<64>(b1r); b1i = wsum<64>(b1i);
  b2r = wsum<64>(b2r); b2i = wsum<64>(b2i);
  const float k1 = 2.0f * PHI1, k2 = 2.0f * PHI2;
  const float invM2 = 1.0f / (float)M2;
  float part = 0.0f;
#pragma unroll
  for (int ii = 0; ii < NR2; ++ii) {
    const int idx = l + 64 * ii;
    const int t = prevM<M2>(idx);
    float sv, cv;
    __sincosf((6.283185307179586f / (float)M2) * (float)t, &sv, &cv);
    float acc = b0 + k1 * (b1r * cv - b1i * sv);
    const float c2 = cv * cv - sv * sv, s2 = 2.0f * sv * cv;
    acc += k2 * (b2r * c2 - b2i * s2);
    part += __logf(acc * invM2 + 1e-6f);
  }
  part = wsum<64>(part);
  if (l == 0) *outp = part * invM2;
}

// Per-half-wave descendant, M2=128.
__device__ __forceinline__ void ddual(float2* Ah, const float2* __restrict__ Vg,
                                      float* __restrict__ outp, int M1, int F,
                                      float xi, int ll) {
  const float sg = 0.8f * xi;
  const float i2s = 1.0f / (2.0f * sg * sg);
#pragma unroll
  for (int ii = 0; ii < 4; ++ii) {
    const int m = ll + 32 * ii;
    float2 acc = make_float2(0.0f, 0.0f);
    for (int q = 0; q < F; ++q) {
      const int f = m + q * 128;
      const float fr = (float)(f < (M1 >> 1) ? f : f - M1) * (1.0f / 2048.0f);
      const float d = fr - xi;
      const float dd = d * d * i2s;
      if (dd < GCUT) {
        const float g = __expf(-dd);
        const float2 vv = Vg[f];
        acc.x += vv.x * g; acc.y += vv.y * g;
      }
    }
    Ah[swz(m)] = acc;
  }
  dif_w<128, true, 32>(Ah, ll);
  const float invM1f = 1.0f / (float)M1;
  float b0 = 0, b1r = 0, b1i = 0, b2r = 0, b2i = 0;
#pragma unroll
  for (int ii = 0; ii < 4; ++ii) {
    const int idx = ll + 32 * ii;
    const float2 zv = Ah[swz(idx)];
    const float u = sqrtf(zv.x * zv.x + zv.y * zv.y) * invM1f;
    const int t = prevM<128>(idx);
    float sv, cv;
    __sincosf((6.283185307179586f / 128.0f) * (float)t, &sv, &cv);
    b0 += u;
    b1r += u * cv; b1i -= u * sv;
    const float c2 = cv * cv - sv * sv, s2 = 2.0f * sv * cv;
    b2r += u * c2; b2i -= u * s2;
  }
  b0 = wsum<32>(b0);
  b1r = wsum<32>(b1r); b1i = wsum<32>(b1i);
  b2r = wsum<32>(b2r); b2i = wsum<32>(b2i);
  const float k1 = 2.0f * PHI1, k2 = 2.0f * PHI2;
  const float invM2 = 1.0f / 128.0f;
  float part = 0.0f;
#pragma unroll
  for (int ii = 0; ii < 4; ++ii) {
    const int idx = ll + 32 * ii;
    const int t = prevM<128>(idx);
    float sv, cv;
    __sincosf((6.283185307179586f / 128.0f) * (float)t, &sv, &cv);
    float acc = b0 + k1 * (b1r * cv - b1i * sv);
    const float c2 = cv * cv - sv * sv, s2 = 2.0f * sv * cv;
    acc += k2 * (b2r * c2 - b2i * s2);
    part += __logf(acc * invM2 + 1e-6f);
  }
  part = wsum<32>(part);
  if (ll == 0) *outp = part * invM2;
}

// kC: 58 classes/signal (2784 blocks), one descendant per slot, no chaining.
// [0,8)   k=1: dblk1024, j1=ci.
// [8,12)  k=2: dwav<512> x4, j1=4(ci-8)+wid; M1 = j1<8?1024:512.
// [12,14) k=3 j1 0-7: dwav<512> x4, M1=1024 F=2.
// [14,18) k=3 j1 8-23: dwav<256> x4; M1 = j1<16?512:256.
// [18,20) k=4 j1 0-7: dwav<256> x4, M1=1024 F=4.
// [20,23) k=4 j1 8-31: ddual x8; M1 by octave.
// [23,58) k=5..9: ddual x8; k blocks per k.
__global__ __launch_bounds__(NTH, 4) void kC(const float2* __restrict__ U1h,
                                             float* __restrict__ out) {
  __shared__ float2 W[2048];
  __shared__ float scr[24];
  const int ci = (int)blockIdx.x / 48;
  const int n  = (int)blockIdx.x % 48;
  const int b = n / 6, c = n % 6;
  const float2* Vbase = U1h + (size_t)n * U1H_STRIDE;
  const int tid = (int)threadIdx.x;
  const int wid = tid >> 6, l = tid & 63;
  const int h = l >> 5, ll = l & 31;
  const int slot = 2 * wid + h;

  if (ci < 8) {
    const int j1 = ci;
    dblk1024(W, scr, Vbase + u1h_off(j1), o2p(out, b, c, j1, 1), xi2f(1));
  } else if (ci < 12) {
    const int j1 = 4 * (ci - 8) + wid;  // 0..15
    const int M1 = (j1 < 8) ? 1024 : 512;
    dwav<512>(W + wid * 512, Vbase + u1h_off(j1), o2p(out, b, c, j1, 2),
              M1, M1 / 512, xi2f(2), l);
  } else if (ci < 14) {
    const int j1 = 4 * (ci - 12) + wid;  // 0..7
    dwav<512>(W + wid * 512, Vbase + u1h_off(j1), o2p(out, b, c, j1, 3),
              1024, 2, xi2f(3), l);
  } else if (ci < 18) {
    const int j1 = 8 + 4 * (ci - 14) + wid;  // 8..23
    const int M1 = (j1 < 16) ? 512 : 256;
    dwav<256>(W + wid * 256, Vbase + u1h_off(j1), o2p(out, b, c, j1, 3),
              M1, M1 / 256, xi2f(3), l);
  } else if (ci < 20) {
    const int j1 = 4 * (ci - 18) + wid;  // 0..7
    dwav<256>(W + wid * 256, Vbase + u1h_off(j1), o2p(out, b, c, j1, 4),
              1024, 4, xi2f(4), l);
  } else if (ci < 23) {
    const int j1 = 8 + 8 * (ci - 20) + slot;  // 8..31
    const int o = j1 >> 3;                    // 1..3
    const int M1 = (o < 3) ? (1024 >> o) : 128;
    ddual(W + slot * 128, Vbase + u1h_off(j1), o2p(out, b, c, j1, 4),
          M1, M1 / 128, xi2f(4), ll);
  } else {
    int g = ci - 23;  // k blocks per k, k=5..9
    int k = 5;
    while (g >= k) { g -= k; ++k; }
    const int j1 = 8 * g + slot;  // octave o = g
    const int M1 = (g < 3) ? (1024 >> g) : 128;
    ddual(W + slot * 128, Vbase + u1h_off(j1), o2p(out, b, c, j1, k),
          M1, M1 / 128, xi2f(k), ll);
  }
}

extern "C" void kernel_launch(void* const* d_in, const int* in_sizes, int n_in,
                              void* d_out, int out_size, void* d_ws, size_t ws_size,
                              hipStream_t stream) {
  (void)in_sizes; (void)n_in; (void)out_size; (void)ws_size;
  const float* x = (const float*)d_in[0];  // [8, 2048, 6] fp32
  float* out = (float*)d_out;              // [8, 440, 6] fp32
  float2* U1h = (float2*)d_ws;                                       // 8.26 MB
  float2* xh = (float2*)((char*)d_ws + (size_t)48 * U1H_STRIDE * sizeof(float2));
  kA<<<dim3(48), dim3(NTH), 0, stream>>>(x, xh);
  kB<<<dim3(19 * 48), dim3(NTH), 0, stream>>>(xh, U1h, out);
  kC<<<dim3(58 * 48), dim3(NTH), 0, stream>>>(U1h, out);
}

// Round 10
// 83.374 us; speedup vs baseline: 1.7822x; 1.0171x over previous
//
#include <hip/hip_runtime.h>

#define NTH 256
#define U1H_STRIDE 21504  // 8*1024 + 8*512 + 8*256 + 56*128

#define PHI1 0.29504296f    // e^{-1.220703125}
#define PHI2 0.0075683594f  // e^{-4.8828125}
#define GCUT 18.0f          // Gaussian support cutoff: e^-18 = 1.5e-8

// Bank swizzle — conflict-free for all in-place strides; swz(i+128)=swz(i)+128.
__device__ __forceinline__ int swz(int i) { return i ^ (((i >> 4) & 3) * 5); }

__device__ __forceinline__ float2 cmul(float2 a, float2 b) {
  return make_float2(a.x * b.x - a.y * b.y, a.x * b.y + a.y * b.x);
}

template <int W>
__device__ __forceinline__ float wsum(float v) {
#pragma unroll
  for (int off = 1; off < W; off <<= 1) v += __shfl_xor(v, off, 64);
  return v;
}

// P(idx): output frequency of storage slot idx after the DIF stage sequence.
template <int M>
__device__ __forceinline__ int prevM(int i) {
  if (M == 128)
    return ((i >> 5) & 3) | (((i >> 3) & 3) << 2) | (((i >> 1) & 3) << 4) | ((i & 1) << 6);
  else if (M == 256)
    return ((i & 3) << 6) | (((i >> 2) & 3) << 4) | (((i >> 4) & 3) << 2) | ((i >> 6) & 3);
  else if (M == 512)
    return ((i >> 7) & 3) | (((i >> 5) & 3) << 2) | (((i >> 3) & 3) << 4) |
           (((i >> 1) & 3) << 6) | ((i & 1) << 8);
  else if (M == 1024)
    return ((i >> 8) & 3) | (((i >> 6) & 3) << 2) | (((i >> 4) & 3) << 4) |
           (((i >> 2) & 3) << 6) | ((i & 3) << 8);
  else
    return ((i >> 9) & 3) | (((i >> 7) & 3) << 2) | (((i >> 5) & 3) << 4) |
           (((i >> 3) & 3) << 6) | (((i >> 1) & 3) << 8) | ((i & 1) << 10);
}

// In-place radix-4 DIF stage; twiddles in registers.
template <bool INV>
__device__ __forceinline__ void dif4(float2* A, int j, int ls, float astep) {
  const int s = 1 << ls;
  const int e = j & (s - 1);
  const int base = ((j >> ls) << (ls + 2)) | e;
  float2 w1;
  __sincosf(astep * (float)e, &w1.y, &w1.x);
  if (INV) w1.y = -w1.y;
  const float2 w2 = cmul(w1, w1);
  const float2 w3 = cmul(w2, w1);
  const float2 a0 = A[swz(base)];
  const float2 a1 = A[swz(base + s)];
  const float2 a2 = A[swz(base + 2 * s)];
  const float2 a3 = A[swz(base + 3 * s)];
  const float t0x = a0.x + a2.x, t0y = a0.y + a2.y;
  const float t1x = a0.x - a2.x, t1y = a0.y - a2.y;
  const float t2x = a1.x + a3.x, t2y = a1.y + a3.y;
  const float bdx = a1.x - a3.x, bdy = a1.y - a3.y;
  const float sgn = INV ? -1.0f : 1.0f;
  const float t3x = sgn * bdy, t3y = -sgn * bdx;
  A[swz(base)]         = make_float2(t0x + t2x, t0y + t2y);
  A[swz(base + s)]     = cmul(make_float2(t1x + t3x, t1y + t3y), w1);
  A[swz(base + 2 * s)] = cmul(make_float2(t0x - t2x, t0y - t2y), w2);
  A[swz(base + 3 * s)] = cmul(make_float2(t1x - t3x, t1y - t3y), w3);
}

// In-place radix-4 DIT stage (transpose network; forward only).
__device__ __forceinline__ void dit4(float2* A, int j, int ls, float astep) {
  const int s = 1 << ls;
  const int e = j & (s - 1);
  const int base = ((j >> ls) << (ls + 2)) | e;
  float2 w1;
  __sincosf(astep * (float)e, &w1.y, &w1.x);
  const float2 w2 = cmul(w1, w1);
  const float2 w3 = cmul(w2, w1);
  const float2 c0 = A[swz(base)];
  const float2 c1 = cmul(A[swz(base + s)], w1);
  const float2 c2 = cmul(A[swz(base + 2 * s)], w2);
  const float2 c3 = cmul(A[swz(base + 3 * s)], w3);
  const float t0x = c0.x + c2.x, t0y = c0.y + c2.y;
  const float t1x = c0.x - c2.x, t1y = c0.y - c2.y;
  const float t2x = c1.x + c3.x, t2y = c1.y + c3.y;
  const float bdx = c1.x - c3.x, bdy = c1.y - c3.y;
  const float t3x = bdy, t3y = -bdx;
  A[swz(base)]         = make_float2(t0x + t2x, t0y + t2y);
  A[swz(base + s)]     = make_float2(t1x + t3x, t1y + t3y);
  A[swz(base + 2 * s)] = make_float2(t0x - t2x, t0y - t2y);
  A[swz(base + 3 * s)] = make_float2(t1x - t3x, t1y - t3y);
}

__device__ __forceinline__ void r2pair(float2* A, int g) {
  const float2 a = A[swz(2 * g)];
  const float2 b = A[swz(2 * g + 1)];
  A[swz(2 * g)]     = make_float2(a.x + b.x, a.y + b.y);
  A[swz(2 * g + 1)] = make_float2(a.x - b.x, a.y - b.y);
}

template <int M> struct LMof { static constexpr int v =
  (M == 2048) ? 11 : (M == 1024) ? 10 : (M == 512) ? 9 : (M == 256) ? 8 : 7; };

// Block-wide in-place DIF: natural -> P-order.
template <int M, bool INV>
__device__ __forceinline__ void dif_blk(float2* A) {
  constexpr int LM = LMof<M>::v;
  constexpr int NB = M / 4;
  const int tid = (int)threadIdx.x;
#pragma unroll
  for (int ls = LM - 2; ls >= (LM & 1); ls -= 2) {
    const float astep = -1.5707963267948966f / (float)(1 << ls);
    __syncthreads();
#pragma unroll
    for (int i = 0; i < NB / NTH; ++i) dif4<INV>(A, tid + NTH * i, ls, astep);
  }
  if (LM & 1) {
    __syncthreads();
#pragma unroll
    for (int i = 0; i < (M / 2) / NTH; ++i) r2pair(A, tid + NTH * i);
  }
  __syncthreads();
}

// Block-wide in-place DIT (forward): P-order -> natural.
template <int M>
__device__ __forceinline__ void dit_blk(float2* A) {
  constexpr int LM = LMof<M>::v;
  constexpr int NB = M / 4;
  const int tid = (int)threadIdx.x;
  if (LM & 1) {
    __syncthreads();
#pragma unroll
    for (int i = 0; i < (M / 2) / NTH; ++i) r2pair(A, tid + NTH * i);
  }
#pragma unroll
  for (int ls = (LM & 1); ls <= LM - 2; ls += 2) {
    const float astep = -1.5707963267948966f / (float)(1 << ls);
    __syncthreads();
#pragma unroll
    for (int i = 0; i < NB / NTH; ++i) dit4(A, tid + NTH * i, ls, astep);
  }
  __syncthreads();
}

// Lane-group FFTs, barrier-free (group-private slice, in-order LDS pipe).
template <int M, bool INV, int LANES>
__device__ __forceinline__ void dif_w(float2* Aw, int l) {
  constexpr int LM = LMof<M>::v;
  constexpr int NB = M / 4;
#pragma unroll
  for (int ls = LM - 2; ls >= (LM & 1); ls -= 2) {
    const float astep = -1.5707963267948966f / (float)(1 << ls);
#pragma unroll
    for (int i = 0; i < NB / LANES; ++i) dif4<INV>(Aw, l + LANES * i, ls, astep);
  }
  if (LM & 1) {
#pragma unroll
    for (int i = 0; i < (M / 2) / LANES; ++i) r2pair(Aw, l + LANES * i);
  }
}

template <int M, int LANES>
__device__ __forceinline__ void dit_w(float2* Aw, int l) {
  constexpr int LM = LMof<M>::v;
  constexpr int NB = M / 4;
  if (LM & 1) {
#pragma unroll
    for (int i = 0; i < (M / 2) / LANES; ++i) r2pair(Aw, l + LANES * i);
  }
#pragma unroll
  for (int ls = (LM & 1); ls <= LM - 2; ls += 2) {
    const float astep = -1.5707963267948966f / (float)(1 << ls);
#pragma unroll
    for (int i = 0; i < NB / LANES; ++i) dit4(Aw, l + LANES * i, ls, astep);
  }
}

// U1h layout: o=0:1024/path; o=1:512; o=2:256; o>=3:128.
__device__ __forceinline__ int u1h_off(int j1) {
  const int o = j1 >> 3;
  if (o == 0) return j1 * 1024;
  if (o == 1) return 8192 + (j1 - 8) * 512;
  if (o == 2) return 12288 + (j1 - 16) * 256;
  return 14336 + (j1 - 24) * 128;
}

__device__ __forceinline__ float* o1p(float* out, int b, int c, int j1) {
  return out + ((size_t)b * 440 + j1) * 6 + c;
}
__device__ __forceinline__ float* o2p(float* out, int b, int c, int j1, int k) {
  return out + ((size_t)b * 440 + 80 + 4 * k * (k - 1) + j1) * 6 + c;
}
__device__ __forceinline__ float xi2f(int k) { return 0.4f * exp2f(-(float)k); }

// ---------------- Stage A: 2048-pt FFT per (b,c) signal ----------------
__global__ __launch_bounds__(NTH) void kA(const float* __restrict__ x,
                                          float2* __restrict__ xh) {
  __shared__ float2 A[2048];
  const int n = blockIdx.x, b = n / 6, c = n % 6;
  const float* xp = x + (size_t)b * (2048 * 6) + c;
#pragma unroll
  for (int i = 0; i < 8; ++i) {
    const int t = (int)threadIdx.x + NTH * i;
    A[swz(t)] = make_float2(xp[t * 6], 0.0f);
  }
  dif_blk<2048, false>(A);
#pragma unroll
  for (int i = 0; i < 8; ++i) {
    const int t = (int)threadIdx.x + NTH * i;
    xh[(size_t)n * 2048 + prevM<2048>(t)] = A[swz(t)];
  }
}

// ================= Stage B: parents; V=U1h -> global; S1 out ===============
// All bodies force-inlined, no cached sincos arrays (spill discipline, r2).

// Block-wide, M1=1024 (j1 0..7).
__device__ __forceinline__ void pblk1024(float2* A, float* scr,
                                         const float2* __restrict__ src,
                                         float2* __restrict__ Vg,
                                         float* __restrict__ outp, int j1) {
  constexpr int M1 = 1024;
  const int tid = (int)threadIdx.x;
  const float xi = 0.4f * exp2f(-0.125f * (float)j1);
  const float sig = 0.1f * xi;
  const float i2s = 1.0f / (2.0f * sig * sig);
#pragma unroll
  for (int i = 0; i < 4; ++i) {
    const int m = tid + NTH * i;
    float2 acc = make_float2(0.0f, 0.0f);
#pragma unroll
    for (int q = 0; q < 2; ++q) {
      const int f = m + q * M1;
      const float fr = (float)(f < 1024 ? f : f - 2048) * (1.0f / 2048.0f);
      const float d = fr - xi;
      const float dd = d * d * i2s;
      if (dd < GCUT) {
        const float g = __expf(-dd);
        const float2 v = src[f];
        acc.x += v.x * g; acc.y += v.y * g;
      }
    }
    A[swz(m)] = acc;
  }
  dif_blk<M1, true>(A);
#pragma unroll
  for (int i = 0; i < 4; ++i) {
    const int m = tid + NTH * i;
    const float2 zv = A[swz(m)];
    A[swz(m)] = make_float2(sqrtf(zv.x * zv.x + zv.y * zv.y) * (1.0f / 2048.0f), 0.0f);
  }
  dit_blk<M1>(A);  // V natural (digit reversal cancels).
#pragma unroll
  for (int i = 0; i < 4; ++i) {  // writeback V (coalesced, natural order)
    const int m = tid + NTH * i;
    Vg[m] = A[swz(m)];
  }
  const float invM = 1.0f / (float)M1;
  const float c0 = A[0].x * invM;  // swz identity for idx<16
  const float2 U1 = A[1], U2 = A[2];
  const float k1 = PHI1 * 2.0f * invM, k2 = PHI2 * 2.0f * invM;
  float part = 0.0f;
#pragma unroll
  for (int i = 0; i < 4; ++i) {
    const int t = tid + NTH * i;
    float sv, cv;
    __sincosf((6.283185307179586f / (float)M1) * (float)t, &sv, &cv);
    float acc = c0 + k1 * (U1.x * cv - U1.y * sv);
    const float c2 = cv * cv - sv * sv, s2 = 2.0f * sv * cv;
    acc += k2 * (U2.x * c2 - U2.y * s2);
    part += __logf(acc + 1e-6f);
  }
  part = wsum<64>(part);
  const int lane = tid & 63, wid = tid >> 6;
  if (lane == 0) scr[wid] = part;
  __syncthreads();
  if (tid == 0) *outp = (scr[0] + scr[1] + scr[2] + scr[3]) * invM;
}

// Per-wave (64 lanes), M1 in {512, 256}.
template <int M1>
__device__ __forceinline__ void pwav(float2* Aw, const float2* __restrict__ src,
                                     float2* __restrict__ Vg,
                                     float* __restrict__ outp, int j1, int l) {
  constexpr int NRW = M1 / 64;
  constexpr int F = 2048 / M1;
  const float xi = 0.4f * exp2f(-0.125f * (float)j1);
  const float sig = 0.1f * xi;
  const float i2s = 1.0f / (2.0f * sig * sig);
#pragma unroll
  for (int i = 0; i < NRW; ++i) {
    const int m = l + 64 * i;
    float2 acc = make_float2(0.0f, 0.0f);
#pragma unroll
    for (int q = 0; q < F; ++q) {
      const int f = m + q * M1;
      const float fr = (float)(f < 1024 ? f : f - 2048) * (1.0f / 2048.0f);
      const float d = fr - xi;
      const float dd = d * d * i2s;
      if (dd < GCUT) {
        const float g = __expf(-dd);
        const float2 v = src[f];
        acc.x += v.x * g; acc.y += v.y * g;
      }
    }
    Aw[swz(m)] = acc;
  }
  dif_w<M1, true, 64>(Aw, l);
#pragma unroll
  for (int i = 0; i < NRW; ++i) {
    const int m = l + 64 * i;
    const float2 zv = Aw[swz(m)];
    Aw[swz(m)] = make_float2(sqrtf(zv.x * zv.x + zv.y * zv.y) * (1.0f / 2048.0f), 0.0f);
  }
  dit_w<M1, 64>(Aw, l);  // V natural
#pragma unroll
  for (int i = 0; i < NRW; ++i) {
    const int m = l + 64 * i;
    Vg[m] = Aw[swz(m)];
  }
  const float invM = 1.0f / (float)M1;
  const float c0 = Aw[0].x * invM;
  const float2 U1 = Aw[1], U2 = Aw[2];
  const float k1 = PHI1 * 2.0f * invM, k2 = PHI2 * 2.0f * invM;
  float part = 0.0f;
#pragma unroll
  for (int i = 0; i < NRW; ++i) {
    const int t = l + 64 * i;
    float sv, cv;
    __sincosf((6.283185307179586f / (float)M1) * (float)t, &sv, &cv);
    float acc = c0 + k1 * (U1.x * cv - U1.y * sv);
    const float c2 = cv * cv - sv * sv, s2 = 2.0f * sv * cv;
    acc += k2 * (U2.x * c2 - U2.y * s2);
    part += __logf(acc + 1e-6f);
  }
  part = wsum<64>(part);
  if (l == 0) *outp = part * invM;
}

// Per-half-wave (32 lanes), M1=128.
__device__ __forceinline__ void pdual(float2* Ah, const float2* __restrict__ src,
                                      float2* __restrict__ Vg,
                                      float* __restrict__ outp, int j1, int ll) {
  const float xi = 0.4f * exp2f(-0.125f * (float)j1);
  const float sig = 0.1f * xi;
  const float i2s = 1.0f / (2.0f * sig * sig);
#pragma unroll
  for (int i = 0; i < 4; ++i) {
    const int m = ll + 32 * i;
    float2 acc = make_float2(0.0f, 0.0f);
#pragma unroll
    for (int q = 0; q < 16; ++q) {
      const int f = m + q * 128;
      const float fr = (float)(f < 1024 ? f : f - 2048) * (1.0f / 2048.0f);
      const float d = fr - xi;
      const float dd = d * d * i2s;
      if (dd < GCUT) {
        const float g = __expf(-dd);
        const float2 v = src[f];
        acc.x += v.x * g; acc.y += v.y * g;
      }
    }
    Ah[swz(m)] = acc;
  }
  dif_w<128, true, 32>(Ah, ll);
#pragma unroll
  for (int i = 0; i < 4; ++i) {
    const int m = ll + 32 * i;
    const float2 zv = Ah[swz(m)];
    Ah[swz(m)] = make_float2(sqrtf(zv.x * zv.x + zv.y * zv.y) * (1.0f / 2048.0f), 0.0f);
  }
  dit_w<128, 32>(Ah, ll);  // V natural
#pragma unroll
  for (int i = 0; i < 4; ++i) {
    const int m = ll + 32 * i;
    Vg[m] = Ah[swz(m)];
  }
  const float invM = 1.0f / 128.0f;
  const float c0 = Ah[0].x * invM;
  const float2 U1 = Ah[1], U2 = Ah[2];
  const float k1 = PHI1 * 2.0f * invM, k2 = PHI2 * 2.0f * invM;
  float part = 0.0f;
#pragma unroll
  for (int i = 0; i < 4; ++i) {
    const int t = ll + 32 * i;
    float sv, cv;
    __sincosf((6.283185307179586f / 128.0f) * (float)t, &sv, &cv);
    float acc = c0 + k1 * (U1.x * cv - U1.y * sv);
    const float c2 = cv * cv - sv * sv, s2 = 2.0f * sv * cv;
    acc += k2 * (U2.x * c2 - U2.y * s2);
    part += __logf(acc + 1e-6f);
  }
  part = wsum<32>(part);
  if (ll == 0) *outp = part * invM;
}

// kB: 19 classes/signal (912 blocks = 3.56/CU: GRID-limited, bound stays 4).
// LDS 2080 float2 = 16.6 KB.
// [0,8) o=0 blk1024; [8,10) o=1 512wav x4; [10,12) o=2 256wav x4;
// [12,19) o>=3 128dual x8.
__global__ __launch_bounds__(NTH, 4) void kB(const float2* __restrict__ xh,
                                             float2* __restrict__ U1h,
                                             float* __restrict__ out) {
  __shared__ float2 A[2080];  // [2048,2080) = scratch floats
  const int ci = (int)blockIdx.x / 48;
  const int n  = (int)blockIdx.x % 48;
  const int b = n / 6, c = n % 6;
  const float2* src = xh + (size_t)n * 2048;
  float2* Vbase = U1h + (size_t)n * U1H_STRIDE;
  const int tid = (int)threadIdx.x;
  const int wid = tid >> 6, l = tid & 63;
  const int h = l >> 5, ll = l & 31;
  const int slot = 2 * wid + h;

  if (ci < 8) {
    const int j1 = ci;
    pblk1024(A, (float*)(A + 2048), src, Vbase + u1h_off(j1), o1p(out, b, c, j1), j1);
  } else if (ci < 10) {
    const int j1 = 8 + 4 * (ci - 8) + wid;
    pwav<512>(A + wid * 512, src, Vbase + u1h_off(j1), o1p(out, b, c, j1), j1, l);
  } else if (ci < 12) {
    const int j1 = 16 + 4 * (ci - 10) + wid;
    pwav<256>(A + wid * 256, src, Vbase + u1h_off(j1), o1p(out, b, c, j1), j1, l);
  } else {
    const int j1 = 24 + 8 * (ci - 12) + slot;
    pdual(A + slot * 128, src, Vbase + u1h_off(j1), o1p(out, b, c, j1), j1, ll);
  }
}

// ================= Stage C: descendants; V from global ====================

// Block-wide 3-bin DFT, M2=1024 (k=1 only; M1=1024, F=1).
__device__ __forceinline__ void dblk1024(float2* A, float* scr,
                                         const float2* __restrict__ Vg,
                                         float* __restrict__ outp, float xi) {
  constexpr int M2 = 1024;
  const int tid = (int)threadIdx.x;
  const float sg = 0.8f * xi;
  const float i2s = 1.0f / (2.0f * sg * sg);
#pragma unroll
  for (int ii = 0; ii < 4; ++ii) {
    const int m = tid + NTH * ii;
    float2 acc = make_float2(0.0f, 0.0f);
    const float fr = (float)(m < 512 ? m : m - 1024) * (1.0f / 2048.0f);
    const float d = fr - xi;
    const float dd = d * d * i2s;
    if (dd < GCUT) {
      const float g = __expf(-dd);
      const float2 vv = Vg[m];
      acc.x = vv.x * g; acc.y = vv.y * g;
    }
    A[swz(m)] = acc;
  }
  dif_blk<M2, true>(A);  // z2 in P-order
  const float invM1f = 1.0f / 1024.0f;
  float b0 = 0, b1r = 0, b1i = 0, b2r = 0, b2i = 0;
#pragma unroll
  for (int ii = 0; ii < 4; ++ii) {
    const int idx = tid + NTH * ii;
    const float2 zv = A[swz(idx)];
    const float u = sqrtf(zv.x * zv.x + zv.y * zv.y) * invM1f;
    const int t = prevM<M2>(idx);
    float sv, cv;
    __sincosf((6.283185307179586f / (float)M2) * (float)t, &sv, &cv);
    b0 += u;
    b1r += u * cv; b1i -= u * sv;
    const float c2 = cv * cv - sv * sv, s2 = 2.0f * sv * cv;
    b2r += u * c2; b2i -= u * s2;
  }
  b0 = wsum<64>(b0);
  b1r = wsum<64>(b1r); b1i = wsum<64>(b1i);
  b2r = wsum<64>(b2r); b2i = wsum<64>(b2i);
  const int lane = tid & 63, wid = tid >> 6;
  if (lane == 0) {
    scr[wid * 5 + 0] = b0;
    scr[wid * 5 + 1] = b1r; scr[wid * 5 + 2] = b1i;
    scr[wid * 5 + 3] = b2r; scr[wid * 5 + 4] = b2i;
  }
  __syncthreads();
  float Bv[5];
#pragma unroll
  for (int bi = 0; bi < 5; ++bi)
    Bv[bi] = scr[bi] + scr[5 + bi] + scr[10 + bi] + scr[15 + bi];
  const float k1 = 2.0f * PHI1, k2 = 2.0f * PHI2;
  const float invM2 = 1.0f / (float)M2;
  float part = 0.0f;
#pragma unroll
  for (int ii = 0; ii < 4; ++ii) {
    const int idx = tid + NTH * ii;
    const int t = prevM<M2>(idx);
    float sv, cv;
    __sincosf((6.283185307179586f / (float)M2) * (float)t, &sv, &cv);
    float acc = Bv[0] + k1 * (Bv[1] * cv - Bv[2] * sv);
    const float c2 = cv * cv - sv * sv, s2 = 2.0f * sv * cv;
    acc += k2 * (Bv[3] * c2 - Bv[4] * s2);
    part += __logf(acc * invM2 + 1e-6f);
  }
  part = wsum<64>(part);
  if (lane == 0) scr[20 + wid] = part;
  __syncthreads();
  if (tid == 0) *outp = (scr[20] + scr[21] + scr[22] + scr[23]) * invM2;
}

// Per-wave descendant, M2 in {512, 256}. No cached sincos arrays.
template <int M2>
__device__ __forceinline__ void dwav(float2* Aw, const float2* __restrict__ Vg,
                                     float* __restrict__ outp, int M1, int F,
                                     float xi, int l) {
  constexpr int NR2 = M2 / 64;
  const float sg = 0.8f * xi;
  const float i2s = 1.0f / (2.0f * sg * sg);
#pragma unroll
  for (int ii = 0; ii < NR2; ++ii) {
    const int m = l + 64 * ii;
    float2 acc = make_float2(0.0f, 0.0f);
    for (int q = 0; q < F; ++q) {
      const int f = m + q * M2;
      const float fr = (float)(f < (M1 >> 1) ? f : f - M1) * (1.0f / 2048.0f);
      const float d = fr - xi;
      const float dd = d * d * i2s;
      if (dd < GCUT) {
        const float g = __expf(-dd);
        const float2 vv = Vg[f];
        acc.x += vv.x * g; acc.y += vv.y * g;
      }
    }
    Aw[swz(m)] = acc;
  }
  dif_w<M2, true, 64>(Aw, l);
  const float invM1f = 1.0f / (float)M1;
  float b0 = 0, b1r = 0, b1i = 0, b2r = 0, b2i = 0;
#pragma unroll
  for (int ii = 0; ii < NR2; ++ii) {
    const int idx = l + 64 * ii;
    const float2 zv = Aw[swz(idx)];
    const float u = sqrtf(zv.x * zv.x + zv.y * zv.y) * invM1f;
    const int t = prevM<M2>(idx);
    float sv, cv;
    __sincosf((6.283185307179586f / (float)M2) * (float)t, &sv, &cv);
    b0 += u;
    b1r += u * cv; b1i -= u * sv;
    const float c2 = cv * cv - sv * sv, s2 = 2.0f * sv * cv;
    b2r += u * c2; b2i -= u * s2;
  }
  b0 = wsum<64>(b0);
  b1r = wsum<64>(b1r); b1i = wsum<64>(b1i);
  b2r = wsum<64>(b2r); b2i = wsum<64>(b2i);
  const float k1 = 2.0f * PHI1, k2 = 2.0f * PHI2;
  const float invM2 = 1.0f / (float)M2;
  float part = 0.0f;
#pragma unroll
  for (int ii = 0; ii < NR2; ++ii) {
    const int idx = l + 64 * ii;
    const int t = prevM<M2>(idx);
    float sv, cv;
    __sincosf((6.283185307179586f / (float)M2) * (float)t, &sv, &cv);
    float acc = b0 + k1 * (b1r * cv - b1i * sv);
    const float c2 = cv * cv - sv * sv, s2 = 2.0f * sv * cv;
    acc += k2 * (b2r * c2 - b2i * s2);
    part += __logf(acc * invM2 + 1e-6f);
  }
  part = wsum<64>(part);
  if (l == 0) *outp = part * invM2;
}

// Per-half-wave descendant, M2=128.
__device__ __forceinline__ void ddual(float2* Ah, const float2* __restrict__ Vg,
                                      float* __restrict__ outp, int M1, int F,
                                      float xi, int ll) {
  const float sg = 0.8f * xi;
  const float i2s = 1.0f / (2.0f * sg * sg);
#pragma unroll
  for (int ii = 0; ii < 4; ++ii) {
    const int m = ll + 32 * ii;
    float2 acc = make_float2(0.0f, 0.0f);
    for (int q = 0; q < F; ++q) {
      const int f = m + q * 128;
      const float fr = (float)(f < (M1 >> 1) ? f : f - M1) * (1.0f / 2048.0f);
      const float d = fr - xi;
      const float dd = d * d * i2s;
      if (dd < GCUT) {
        const float g = __expf(-dd);
        const float2 vv = Vg[f];
        acc.x += vv.x * g; acc.y += vv.y * g;
      }
    }
    Ah[swz(m)] = acc;
  }
  dif_w<128, true, 32>(Ah, ll);
  const float invM1f = 1.0f / (float)M1;
  float b0 = 0, b1r = 0, b1i = 0, b2r = 0, b2i = 0;
#pragma unroll
  for (int ii = 0; ii < 4; ++ii) {
    const int idx = ll + 32 * ii;
    const float2 zv = Ah[swz(idx)];
    const float u = sqrtf(zv.x * zv.x + zv.y * zv.y) * invM1f;
    const int t = prevM<128>(idx);
    float sv, cv;
    __sincosf((6.283185307179586f / 128.0f) * (float)t, &sv, &cv);
    b0 += u;
    b1r += u * cv; b1i -= u * sv;
    const float c2 = cv * cv - sv * sv, s2 = 2.0f * sv * cv;
    b2r += u * c2; b2i -= u * s2;
  }
  b0 = wsum<32>(b0);
  b1r = wsum<32>(b1r); b1i = wsum<32>(b1i);
  b2r = wsum<32>(b2r); b2i = wsum<32>(b2i);
  const float k1 = 2.0f * PHI1, k2 = 2.0f * PHI2;
  const float invM2 = 1.0f / 128.0f;
  float part = 0.0f;
#pragma unroll
  for (int ii = 0; ii < 4; ++ii) {
    const int idx = ll + 32 * ii;
    const int t = prevM<128>(idx);
    float sv, cv;
    __sincosf((6.283185307179586f / 128.0f) * (float)t, &sv, &cv);
    float acc = b0 + k1 * (b1r * cv - b1i * sv);
    const float c2 = cv * cv - sv * sv, s2 = 2.0f * sv * cv;
    acc += k2 * (b2r * c2 - b2i * s2);
    part += __logf(acc * invM2 + 1e-6f);
  }
  part = wsum<32>(part);
  if (ll == 0) *outp = part * invM2;
}

// kC: 58 classes/signal (2784 blocks = 10.9/CU: grid NOT the limit).
// __launch_bounds__(NTH, 6): VGPR cap 84 (bound-4 natural need is >64 per r8's
// regression, likely 70-84) -> 6 blocks/CU vs 4, +50% waves on the
// LDS-latency-bound kernel. Bound 8 (cap 64) regressed (r8); 6 is the untested
// middle. Tripwire: spills would show as kC WRITE_SIZE >> 1 MB.
// [0,8)   k=1: dblk1024, j1=ci.
// [8,12)  k=2: dwav<512> x4, j1=4(ci-8)+wid; M1 = j1<8?1024:512.
// [12,14) k=3 j1 0-7: dwav<512> x4, M1=1024 F=2.
// [14,18) k=3 j1 8-23: dwav<256> x4; M1 = j1<16?512:256.
// [18,20) k=4 j1 0-7: dwav<256> x4, M1=1024 F=4.
// [20,23) k=4 j1 8-31: ddual x8; M1 by octave.
// [23,58) k=5..9: ddual x8; k blocks per k.
__global__ __launch_bounds__(NTH, 6) void kC(const float2* __restrict__ U1h,
                                             float* __restrict__ out) {
  __shared__ float2 W[2048];
  __shared__ float scr[24];
  const int ci = (int)blockIdx.x / 48;
  const int n  = (int)blockIdx.x % 48;
  const int b = n / 6, c = n % 6;
  const float2* Vbase = U1h + (size_t)n * U1H_STRIDE;
  const int tid = (int)threadIdx.x;
  const int wid = tid >> 6, l = tid & 63;
  const int h = l >> 5, ll = l & 31;
  const int slot = 2 * wid + h;

  if (ci < 8) {
    const int j1 = ci;
    dblk1024(W, scr, Vbase + u1h_off(j1), o2p(out, b, c, j1, 1), xi2f(1));
  } else if (ci < 12) {
    const int j1 = 4 * (ci - 8) + wid;  // 0..15
    const int M1 = (j1 < 8) ? 1024 : 512;
    dwav<512>(W + wid * 512, Vbase + u1h_off(j1), o2p(out, b, c, j1, 2),
              M1, M1 / 512, xi2f(2), l);
  } else if (ci < 14) {
    const int j1 = 4 * (ci - 12) + wid;  // 0..7
    dwav<512>(W + wid * 512, Vbase + u1h_off(j1), o2p(out, b, c, j1, 3),
              1024, 2, xi2f(3), l);
  } else if (ci < 18) {
    const int j1 = 8 + 4 * (ci - 14) + wid;  // 8..23
    const int M1 = (j1 < 16) ? 512 : 256;
    dwav<256>(W + wid * 256, Vbase + u1h_off(j1), o2p(out, b, c, j1, 3),
              M1, M1 / 256, xi2f(3), l);
  } else if (ci < 20) {
    const int j1 = 4 * (ci - 18) + wid;  // 0..7
    dwav<256>(W + wid * 256, Vbase + u1h_off(j1), o2p(out, b, c, j1, 4),
              1024, 4, xi2f(4), l);
  } else if (ci < 23) {
    const int j1 = 8 + 8 * (ci - 20) + slot;  // 8..31
    const int o = j1 >> 3;                    // 1..3
    const int M1 = (o < 3) ? (1024 >> o) : 128;
    ddual(W + slot * 128, Vbase + u1h_off(j1), o2p(out, b, c, j1, 4),
          M1, M1 / 128, xi2f(4), ll);
  } else {
    int g = ci - 23;  // k blocks per k, k=5..9
    int k = 5;
    while (g >= k) { g -= k; ++k; }
    const int j1 = 8 * g + slot;  // octave o = g
    const int M1 = (g < 3) ? (1024 >> g) : 128;
    ddual(W + slot * 128, Vbase + u1h_off(j1), o2p(out, b, c, j1, k),
          M1, M1 / 128, xi2f(k), ll);
  }
}

extern "C" void kernel_launch(void* const* d_in, const int* in_sizes, int n_in,
                              void* d_out, int out_size, void* d_ws, size_t ws_size,
                              hipStream_t stream) {
  (void)in_sizes; (void)n_in; (void)out_size; (void)ws_size;
  const float* x = (const float*)d_in[0];  // [8, 2048, 6] fp32
  float* out = (float*)d_out;              // [8, 440, 6] fp32
  float2* U1h = (float2*)d_ws;                                       // 8.26 MB
  float2* xh = (float2*)((char*)d_ws + (size_t)48 * U1H_STRIDE * sizeof(float2));
  kA<<<dim3(48), dim3(NTH), 0, stream>>>(x, xh);
  kB<<<dim3(19 * 48), dim3(NTH), 0, stream>>>(xh, U1h, out);
  kC<<<dim3(58 * 48), dim3(NTH), 0, stream>>>(U1h, out);
}